// Round 1
// baseline (8270.985 us; speedup 1.0000x reference)
//
#include <hip/hip_runtime.h>
#include <hip/hip_bf16.h>
#include <math.h>

#define NNODES 50000
#define NEDGES 800000
#define DIN 128
#define DHID 128
#define DOUTF 64

// ---------------- CSR build ----------------

__global__ void count_kernel(const int* __restrict__ dst, int* __restrict__ cnt, int E) {
    int e = blockIdx.x * 256 + threadIdx.x;
    if (e < E) atomicAdd(&cnt[dst[e]], 1);
}

__global__ void scan_kernel(const int* __restrict__ cnt, int* __restrict__ offs, int n) {
    __shared__ int sdata[1024];
    int tid = threadIdx.x;
    int carry = 0;
    for (int base = 0; base < n; base += 1024) {
        int i = base + tid;
        int v = (i < n) ? cnt[i] : 0;
        sdata[tid] = v;
        __syncthreads();
        for (int off = 1; off < 1024; off <<= 1) {
            int t = (tid >= off) ? sdata[tid - off] : 0;
            __syncthreads();
            sdata[tid] += t;
            __syncthreads();
        }
        int incl = sdata[tid];
        int total = sdata[1023];
        if (i < n) offs[i] = carry + incl - v;   // exclusive
        carry += total;
        __syncthreads();
    }
    if (tid == 0) offs[n] = carry;
}

__global__ void fill_kernel(const int* __restrict__ src, const int* __restrict__ dst,
                            const float* __restrict__ ew,
                            const int* __restrict__ offs, int* __restrict__ cursor,
                            int* __restrict__ srcs_sorted, float* __restrict__ ews_sorted, int E) {
    int e = blockIdx.x * 256 + threadIdx.x;
    if (e < E) {
        int d = dst[e];
        int p = atomicAdd(&cursor[d], 1);
        int slot = offs[d] + p;
        srcs_sorted[slot] = src[e];
        ews_sorted[slot]  = ew[e];
    }
}

// ---------------- scatter-mean as node-centric gather ----------------
// one wave (64 lanes) per node; lane owns 2 features (float2) of the 128.

__global__ void gather_mean_kernel(const float* __restrict__ F,     // [N,128]
                                   const int* __restrict__ offs,
                                   const int* __restrict__ srcs,
                                   const float* __restrict__ ews,
                                   float* __restrict__ outmean,     // [N,128]
                                   int n_nodes) {
    int wave = (blockIdx.x * blockDim.x + threadIdx.x) >> 6;
    int lane = threadIdx.x & 63;
    if (wave >= n_nodes) return;
    int beg = offs[wave], end = offs[wave + 1];
    float2 acc = make_float2(0.f, 0.f);
    const float2* Fp = (const float2*)F;
    for (int s = beg; s < end; ++s) {
        int src = srcs[s];
        float w = ews[s];
        float2 v = Fp[(size_t)src * 64 + lane];
        acc.x += v.x * w;
        acc.y += v.y * w;
    }
    float inv = 1.f / fmaxf((float)(end - beg), 1.f);
    ((float2*)outmean)[(size_t)wave * 64 + lane] = make_float2(acc.x * inv, acc.y * inv);
}

// ---------------- fused linear: out = mean @ Wrel^T + brel + x @ Wroot^T (+ELU) ----------------
// block = 256 threads, TN=32 nodes staged in LDS; thread owns one output col o,
// computes TN/G nodes (G = 256/DOUT groups).

template <int DOUT, bool ELU>
__global__ void linear_kernel(const float* __restrict__ mean_in,   // [N,128]
                              const float* __restrict__ x_in,      // [N,128]
                              const float* __restrict__ Wrel,      // [DOUT,128]
                              const float* __restrict__ brel,      // [DOUT]
                              const float* __restrict__ Wroot,     // [DOUT,128]
                              float* __restrict__ out,             // [N,DOUT]
                              int n_nodes) {
    constexpr int TN  = 32;
    constexpr int G   = 256 / DOUT;
    constexpr int NPG = TN / G;
    __shared__ float s_mean[TN][128];
    __shared__ float s_x[TN][128];
    int tid = threadIdx.x;
    int o = tid % DOUT;
    int g = tid / DOUT;
    int base = blockIdx.x * TN;

    for (int idx = tid; idx < TN * 32; idx += 256) {
        int node = idx >> 5, c = idx & 31;
        int gn = base + node;
        float4 m = make_float4(0.f, 0.f, 0.f, 0.f), xv = m;
        if (gn < n_nodes) {
            m  = ((const float4*)(mean_in + (size_t)gn * 128))[c];
            xv = ((const float4*)(x_in   + (size_t)gn * 128))[c];
        }
        ((float4*)s_mean[node])[c] = m;
        ((float4*)s_x[node])[c]    = xv;
    }
    __syncthreads();

    float acc[NPG];
#pragma unroll
    for (int i = 0; i < NPG; ++i) acc[i] = 0.f;

    const float4* wr_p = (const float4*)(Wrel  + (size_t)o * 128);
    const float4* wt_p = (const float4*)(Wroot + (size_t)o * 128);
#pragma unroll
    for (int kc = 0; kc < 32; ++kc) {
        float4 wr = wr_p[kc];
        float4 wt = wt_p[kc];
#pragma unroll
        for (int i = 0; i < NPG; ++i) {
            int node = g * NPG + i;
            float4 mv = ((const float4*)s_mean[node])[kc];
            float4 xv = ((const float4*)s_x[node])[kc];
            acc[i] += mv.x * wr.x + mv.y * wr.y + mv.z * wr.z + mv.w * wr.w
                    + xv.x * wt.x + xv.y * wt.y + xv.z * wt.z + xv.w * wt.w;
        }
    }
    float b = brel[o];
#pragma unroll
    for (int i = 0; i < NPG; ++i) {
        int gn = base + g * NPG + i;
        if (gn < n_nodes) {
            float v = acc[i] + b;
            if (ELU) v = (v > 0.f) ? v : expm1f(v);
            out[(size_t)gn * DOUT + o] = v;
        }
    }
}

extern "C" void kernel_launch(void* const* d_in, const int* in_sizes, int n_in,
                              void* d_out, int out_size, void* d_ws, size_t ws_size,
                              hipStream_t stream) {
    const float* x        = (const float*)d_in[0];
    const int*   eidx     = (const int*)d_in[1];
    const float* eattr    = (const float*)d_in[2];
    const float* W1_rel   = (const float*)d_in[3];
    const float* b1_rel   = (const float*)d_in[4];
    const float* W1_root  = (const float*)d_in[5];
    const float* Wmu_rel  = (const float*)d_in[6];
    const float* bmu_rel  = (const float*)d_in[7];
    const float* Wmu_root = (const float*)d_in[8];
    const float* Wlv_rel  = (const float*)d_in[9];
    const float* blv_rel  = (const float*)d_in[10];
    const float* Wlv_root = (const float*)d_in[11];
    float* out = (float*)d_out;

    const int N = NNODES, E = NEDGES;
    const int* src = eidx;
    const int* dst = eidx + E;

    char* ws = (char*)d_ws;
    int* cnt    = (int*)ws;           // N
    int* cursor = cnt + N;            // N
    int* offs   = cursor + N;         // N+1
    size_t off = (((size_t)(3 * N + 1)) * 4 + 15) & ~(size_t)15;
    int*   srcs_sorted = (int*)(ws + off);   off += (size_t)E * 4;
    float* ews_sorted  = (float*)(ws + off); off += (size_t)E * 4;
    float* mean1 = (float*)(ws + off);       off += (size_t)N * 128 * 4;  // then h in-place
    float* mean2 = (float*)(ws + off);

    hipMemsetAsync(cnt, 0, (size_t)N * 4, stream);
    hipMemsetAsync(cursor, 0, (size_t)N * 4, stream);

    count_kernel<<<(E + 255) / 256, 256, 0, stream>>>(dst, cnt, E);
    scan_kernel<<<1, 1024, 0, stream>>>(cnt, offs, N);
    fill_kernel<<<(E + 255) / 256, 256, 0, stream>>>(src, dst, eattr, offs, cursor,
                                                     srcs_sorted, ews_sorted, E);

    // pass 1: mean of x over incoming edges
    gather_mean_kernel<<<(N + 3) / 4, 256, 0, stream>>>(x, offs, srcs_sorted, ews_sorted, mean1, N);
    // h = elu(mean1 @ W1_rel^T + b1 + x @ W1_root^T), in-place over mean1
    linear_kernel<128, true><<<(N + 31) / 32, 256, 0, stream>>>(mean1, x, W1_rel, b1_rel, W1_root, mean1, N);
    // pass 2: mean of h
    gather_mean_kernel<<<(N + 3) / 4, 256, 0, stream>>>(mean1, offs, srcs_sorted, ews_sorted, mean2, N);
    // mu and logvar
    linear_kernel<64, false><<<(N + 31) / 32, 256, 0, stream>>>(mean2, mean1, Wmu_rel, bmu_rel, Wmu_root, out, N);
    linear_kernel<64, false><<<(N + 31) / 32, 256, 0, stream>>>(mean2, mean1, Wlv_rel, blv_rel, Wlv_root, out + (size_t)N * DOUTF, N);
}

// Round 2
// 569.446 us; speedup vs baseline: 14.5246x; 14.5246x over previous
//
#include <hip/hip_runtime.h>
#include <hip/hip_bf16.h>
#include <math.h>

#define NNODES 50000
#define NEDGES 800000
#define DIN 128
#define DHID 128
#define DOUTF 64

// ---------------- CSR build ----------------

__global__ __launch_bounds__(256)
void count_kernel(const int* __restrict__ dst, int* __restrict__ cnt, int E) {
    int e = blockIdx.x * 256 + threadIdx.x;
    if (e < E) atomicAdd(&cnt[dst[e]], 1);
}

__global__ __launch_bounds__(1024)
void scan_kernel(const int* __restrict__ cnt, int* __restrict__ offs, int n) {
    __shared__ int sdata[1024];
    int tid = threadIdx.x;
    int carry = 0;
    for (int base = 0; base < n; base += 1024) {
        int i = base + tid;
        int v = (i < n) ? cnt[i] : 0;
        sdata[tid] = v;
        __syncthreads();
        for (int off = 1; off < 1024; off <<= 1) {
            int t = (tid >= off) ? sdata[tid - off] : 0;
            __syncthreads();
            sdata[tid] += t;
            __syncthreads();
        }
        int incl = sdata[tid];
        int total = sdata[1023];
        if (i < n) offs[i] = carry + incl - v;   // exclusive
        carry += total;
        __syncthreads();
    }
    if (tid == 0) offs[n] = carry;
}

__global__ __launch_bounds__(256)
void fill_kernel(const int* __restrict__ src, const int* __restrict__ dst,
                 const float* __restrict__ ew,
                 const int* __restrict__ offs, int* __restrict__ cursor,
                 int* __restrict__ srcs_sorted, float* __restrict__ ews_sorted, int E) {
    int e = blockIdx.x * 256 + threadIdx.x;
    if (e < E) {
        int d = dst[e];
        int p = atomicAdd(&cursor[d], 1);
        int slot = offs[d] + p;
        srcs_sorted[slot] = src[e];
        ews_sorted[slot]  = ew[e];
    }
}

// ---------------- scatter-mean as node-centric gather ----------------
// one wave (64 lanes) per node; lane owns 2 features (float2) of the 128.

__global__ __launch_bounds__(256)
void gather_mean_kernel(const float* __restrict__ F,     // [N,128]
                        const int* __restrict__ offs,
                        const int* __restrict__ srcs,
                        const float* __restrict__ ews,
                        float* __restrict__ outmean,     // [N,128]
                        int n_nodes) {
    int wave = (blockIdx.x * blockDim.x + threadIdx.x) >> 6;
    int lane = threadIdx.x & 63;
    if (wave >= n_nodes) return;
    int beg = offs[wave], end = offs[wave + 1];
    float2 acc = make_float2(0.f, 0.f);
    const float2* Fp = (const float2*)F;
    for (int s = beg; s < end; ++s) {
        int src = srcs[s];
        float w = ews[s];
        float2 v = Fp[(size_t)src * 64 + lane];
        acc.x += v.x * w;
        acc.y += v.y * w;
    }
    float inv = 1.f / fmaxf((float)(end - beg), 1.f);
    ((float2*)outmean)[(size_t)wave * 64 + lane] = make_float2(acc.x * inv, acc.y * inv);
}

// ---------------- fused linear: out = mean @ Wrel^T + brel + x @ Wroot^T (+ELU) ----------------
// block = 256 threads, TN=32 nodes staged in LDS; thread owns one output col o.
// __launch_bounds__(256): lift the 64-VGPR cap (no-launch_bounds default assumes
// 1024-thread blocks) that caused ~16KB/thread scratch spill of the hoisted
// LDS-read temps. kc unroll capped at 2 to bound live float4 temporaries.

template <int DOUT, bool ELU>
__global__ __launch_bounds__(256)
void linear_kernel(const float* __restrict__ mean_in,   // [N,128]
                   const float* __restrict__ x_in,      // [N,128]
                   const float* __restrict__ Wrel,      // [DOUT,128]
                   const float* __restrict__ brel,      // [DOUT]
                   const float* __restrict__ Wroot,     // [DOUT,128]
                   float* __restrict__ out,             // [N,DOUT]
                   int n_nodes) {
    constexpr int TN  = 32;
    constexpr int G   = 256 / DOUT;
    constexpr int NPG = TN / G;
    __shared__ float s_mean[TN][128];
    __shared__ float s_x[TN][128];
    int tid = threadIdx.x;
    int o = tid % DOUT;
    int g = tid / DOUT;
    int base = blockIdx.x * TN;

    for (int idx = tid; idx < TN * 32; idx += 256) {
        int node = idx >> 5, c = idx & 31;
        int gn = base + node;
        float4 m = make_float4(0.f, 0.f, 0.f, 0.f), xv = m;
        if (gn < n_nodes) {
            m  = ((const float4*)(mean_in + (size_t)gn * 128))[c];
            xv = ((const float4*)(x_in   + (size_t)gn * 128))[c];
        }
        ((float4*)s_mean[node])[c] = m;
        ((float4*)s_x[node])[c]    = xv;
    }
    __syncthreads();

    float acc[NPG];
#pragma unroll
    for (int i = 0; i < NPG; ++i) acc[i] = 0.f;

    const float4* wr_p = (const float4*)(Wrel  + (size_t)o * 128);
    const float4* wt_p = (const float4*)(Wroot + (size_t)o * 128);
#pragma unroll 2
    for (int kc = 0; kc < 32; ++kc) {
        float4 wr = wr_p[kc];
        float4 wt = wt_p[kc];
#pragma unroll
        for (int i = 0; i < NPG; ++i) {
            int node = g * NPG + i;
            float4 mv = ((const float4*)s_mean[node])[kc];
            float4 xv = ((const float4*)s_x[node])[kc];
            acc[i] += mv.x * wr.x + mv.y * wr.y + mv.z * wr.z + mv.w * wr.w
                    + xv.x * wt.x + xv.y * wt.y + xv.z * wt.z + xv.w * wt.w;
        }
    }
    float b = brel[o];
#pragma unroll
    for (int i = 0; i < NPG; ++i) {
        int gn = base + g * NPG + i;
        if (gn < n_nodes) {
            float v = acc[i] + b;
            if (ELU) v = (v > 0.f) ? v : expm1f(v);
            out[(size_t)gn * DOUT + o] = v;
        }
    }
}

extern "C" void kernel_launch(void* const* d_in, const int* in_sizes, int n_in,
                              void* d_out, int out_size, void* d_ws, size_t ws_size,
                              hipStream_t stream) {
    const float* x        = (const float*)d_in[0];
    const int*   eidx     = (const int*)d_in[1];
    const float* eattr    = (const float*)d_in[2];
    const float* W1_rel   = (const float*)d_in[3];
    const float* b1_rel   = (const float*)d_in[4];
    const float* W1_root  = (const float*)d_in[5];
    const float* Wmu_rel  = (const float*)d_in[6];
    const float* bmu_rel  = (const float*)d_in[7];
    const float* Wmu_root = (const float*)d_in[8];
    const float* Wlv_rel  = (const float*)d_in[9];
    const float* blv_rel  = (const float*)d_in[10];
    const float* Wlv_root = (const float*)d_in[11];
    float* out = (float*)d_out;

    const int N = NNODES, E = NEDGES;
    const int* src = eidx;
    const int* dst = eidx + E;

    char* ws = (char*)d_ws;
    int* cnt    = (int*)ws;           // N
    int* cursor = cnt + N;            // N
    int* offs   = cursor + N;         // N+1
    size_t off = (((size_t)(3 * N + 1)) * 4 + 15) & ~(size_t)15;
    int*   srcs_sorted = (int*)(ws + off);   off += (size_t)E * 4;
    float* ews_sorted  = (float*)(ws + off); off += (size_t)E * 4;
    float* mean1 = (float*)(ws + off);       off += (size_t)N * 128 * 4;  // then h in-place
    float* mean2 = (float*)(ws + off);

    hipMemsetAsync(cnt, 0, (size_t)N * 4, stream);
    hipMemsetAsync(cursor, 0, (size_t)N * 4, stream);

    count_kernel<<<(E + 255) / 256, 256, 0, stream>>>(dst, cnt, E);
    scan_kernel<<<1, 1024, 0, stream>>>(cnt, offs, N);
    fill_kernel<<<(E + 255) / 256, 256, 0, stream>>>(src, dst, eattr, offs, cursor,
                                                     srcs_sorted, ews_sorted, E);

    // pass 1: mean of x over incoming edges
    gather_mean_kernel<<<(N + 3) / 4, 256, 0, stream>>>(x, offs, srcs_sorted, ews_sorted, mean1, N);
    // h = elu(mean1 @ W1_rel^T + b1 + x @ W1_root^T), in-place over mean1
    linear_kernel<128, true><<<(N + 31) / 32, 256, 0, stream>>>(mean1, x, W1_rel, b1_rel, W1_root, mean1, N);
    // pass 2: mean of h
    gather_mean_kernel<<<(N + 3) / 4, 256, 0, stream>>>(mean1, offs, srcs_sorted, ews_sorted, mean2, N);
    // mu and logvar
    linear_kernel<64, false><<<(N + 31) / 32, 256, 0, stream>>>(mean2, mean1, Wmu_rel, bmu_rel, Wmu_root, out, N);
    linear_kernel<64, false><<<(N + 31) / 32, 256, 0, stream>>>(mean2, mean1, Wlv_rel, blv_rel, Wlv_root, out + (size_t)N * DOUTF, N);
}

// Round 3
// 359.859 us; speedup vs baseline: 22.9839x; 1.5824x over previous
//
#include <hip/hip_runtime.h>
#include <hip/hip_bf16.h>
#include <math.h>

#define NNODES 50000
#define NEDGES 800000

using short8 = __attribute__((ext_vector_type(8))) short;
using f32x4  = __attribute__((ext_vector_type(4))) float;

__device__ __forceinline__ short f2bf(float f) {
    __hip_bfloat16 h = __float2bfloat16(f);
    return *reinterpret_cast<short*>(&h);
}

// ---------------- dtype conversion ----------------

__global__ __launch_bounds__(256)
void cvt_x_kernel(const float* __restrict__ in, __hip_bfloat16* __restrict__ out, int n8) {
    int i = blockIdx.x * 256 + threadIdx.x;
    if (i >= n8) return;
    const float4* p = (const float4*)in + (size_t)i * 2;
    float4 a = p[0], b = p[1];
    short8 o;
    o[0] = f2bf(a.x); o[1] = f2bf(a.y); o[2] = f2bf(a.z); o[3] = f2bf(a.w);
    o[4] = f2bf(b.x); o[5] = f2bf(b.y); o[6] = f2bf(b.z); o[7] = f2bf(b.w);
    *reinterpret_cast<short8*>((short*)out + (size_t)i * 8) = o;
}

// Wb layout (elems): W1_rel@0, W1_root@16384, Wmu_rel@32768, Wmu_root@40960,
//                    Wlv_rel@49152, Wlv_root@57344  (total 65536)
__global__ __launch_bounds__(256)
void cvt_weights_kernel(const float* __restrict__ w0, const float* __restrict__ w1,
                        const float* __restrict__ w2, const float* __restrict__ w3,
                        const float* __restrict__ w4, const float* __restrict__ w5,
                        __hip_bfloat16* __restrict__ out) {
    int i = blockIdx.x * 256 + threadIdx.x;   // 256 blocks -> 65536
    const float* src; int off;
    if      (i < 16384) { src = w0; off = 0; }
    else if (i < 32768) { src = w1; off = 16384; }
    else if (i < 40960) { src = w2; off = 32768; }
    else if (i < 49152) { src = w3; off = 40960; }
    else if (i < 57344) { src = w4; off = 49152; }
    else                { src = w5; off = 57344; }
    out[i] = __float2bfloat16(src[i - off]);
}

// ---------------- CSR build ----------------

__global__ __launch_bounds__(256)
void count_kernel(const int* __restrict__ dst, int* __restrict__ cnt, int E) {
    int e = blockIdx.x * 256 + threadIdx.x;
    if (e < E) atomicAdd(&cnt[dst[e]], 1);
}

// hierarchical scan: per-block inclusive scan -> excl + block sums
__global__ __launch_bounds__(1024)
void scan1_kernel(const int* __restrict__ cnt, int* __restrict__ excl,
                  int* __restrict__ bsum, int n) {
    __shared__ int sdata[1024];
    int tid = threadIdx.x;
    int i = blockIdx.x * 1024 + tid;
    int v = (i < n) ? cnt[i] : 0;
    sdata[tid] = v;
    __syncthreads();
    for (int off = 1; off < 1024; off <<= 1) {
        int t = (tid >= off) ? sdata[tid - off] : 0;
        __syncthreads();
        sdata[tid] += t;
        __syncthreads();
    }
    if (i < n) excl[i] = sdata[tid] - v;
    if (tid == 1023) bsum[blockIdx.x] = sdata[1023];
}

__global__ void scan2_kernel(int* __restrict__ bsum, int nb) {
    if (threadIdx.x == 0 && blockIdx.x == 0) {
        int c = 0;
        for (int b = 0; b < nb; ++b) { int t = bsum[b]; bsum[b] = c; c += t; }
        bsum[nb] = c;
    }
}

__global__ __launch_bounds__(1024)
void scan3_kernel(const int* __restrict__ excl, const int* __restrict__ bsum,
                  int* __restrict__ offs, int n, int nb) {
    int i = blockIdx.x * 1024 + threadIdx.x;
    if (i < n) offs[i] = excl[i] + bsum[i >> 10];
    if (i == 0) offs[n] = bsum[nb];
}

__global__ __launch_bounds__(256)
void fill_kernel(const int* __restrict__ src, const int* __restrict__ dst,
                 const float* __restrict__ ew,
                 const int* __restrict__ offs, int* __restrict__ cursor,
                 int* __restrict__ srcs_sorted, float* __restrict__ ews_sorted, int E) {
    int e = blockIdx.x * 256 + threadIdx.x;
    if (e < E) {
        int d = dst[e];
        int p = atomicAdd(&cursor[d], 1);
        int slot = offs[d] + p;
        srcs_sorted[slot] = src[e];
        ews_sorted[slot]  = ew[e];
    }
}

// ---------------- scatter-mean as node-centric gather (bf16 features) ----------------
// one wave per node; lane owns 2 bf16 features (one uint). fp32 accumulate.

__global__ __launch_bounds__(256)
void gather_mean_kernel(const unsigned int* __restrict__ Fb,   // [N,64] uints = [N,128] bf16
                        const int* __restrict__ offs,
                        const int* __restrict__ srcs,
                        const float* __restrict__ ews,
                        unsigned int* __restrict__ outb,       // [N,64] uints
                        int n_nodes) {
    int wave = (blockIdx.x * blockDim.x + threadIdx.x) >> 6;
    int lane = threadIdx.x & 63;
    if (wave >= n_nodes) return;
    int beg = offs[wave], end = offs[wave + 1];
    float ax = 0.f, ay = 0.f;
    for (int s = beg; s < end; ++s) {
        int src = srcs[s];
        float w = ews[s];
        unsigned int v = Fb[(size_t)src * 64 + lane];
        ax += __uint_as_float(v << 16) * w;            // feature 2*lane
        ay += __uint_as_float(v & 0xffff0000u) * w;    // feature 2*lane+1
    }
    float inv = 1.f / fmaxf((float)(end - beg), 1.f);
    unsigned int lo = (unsigned int)(unsigned short)f2bf(ax * inv);
    unsigned int hi = (unsigned int)(unsigned short)f2bf(ay * inv);
    outb[(size_t)wave * 64 + lane] = lo | (hi << 16);
}

// ---------------- MFMA linears ----------------
// mfma_f32_16x16x32_bf16: A lane layout row=l&15, k=8*(l>>4)+j ; B col=l&15, same k;
// C/D: col=lane&15, row=(lane>>4)*4+reg  [learn_hip m89].
// Block = 4 waves, 64 nodes; wave w -> nodes [base+16w, base+16w+16).

// layer1: h = elu(mean1 @ W1rel^T + b1 + x @ W1root^T), bf16 out
__global__ __launch_bounds__(256)
void linear1_mfma(const __hip_bfloat16* __restrict__ Ab1,  // mean1b [N,128]
                  const __hip_bfloat16* __restrict__ Ab2,  // xb [N,128]
                  const __hip_bfloat16* __restrict__ Wb,
                  const float* __restrict__ bias,          // [128]
                  __hip_bfloat16* __restrict__ outb,       // hb [N,128]
                  int n_nodes) {
    int wid  = threadIdx.x >> 6;
    int lane = threadIdx.x & 63;
    int nodeBase = blockIdx.x * 64 + wid * 16;
    int m  = lane & 15;
    int kq = lane >> 4;
    int node = nodeBase + m;
    int nodeC = (node < n_nodes) ? node : (n_nodes - 1);

    short8 a1[4], a2[4];
    const short* A1p = (const short*)Ab1 + (size_t)nodeC * 128 + kq * 8;
    const short* A2p = (const short*)Ab2 + (size_t)nodeC * 128 + kq * 8;
#pragma unroll
    for (int kk = 0; kk < 4; ++kk) {
        a1[kk] = *(const short8*)(A1p + kk * 32);
        a2[kk] = *(const short8*)(A2p + kk * 32);
    }
    const short* Wrel  = (const short*)Wb;           // W1_rel
    const short* Wroot = (const short*)Wb + 16384;   // W1_root

#pragma unroll
    for (int c = 0; c < 8; ++c) {
        f32x4 acc = {0.f, 0.f, 0.f, 0.f};
        const short* b1p = Wrel  + (size_t)(c * 16 + m) * 128 + kq * 8;
        const short* b2p = Wroot + (size_t)(c * 16 + m) * 128 + kq * 8;
#pragma unroll
        for (int kk = 0; kk < 4; ++kk) {
            short8 bw1 = *(const short8*)(b1p + kk * 32);
            acc = __builtin_amdgcn_mfma_f32_16x16x32_bf16(a1[kk], bw1, acc, 0, 0, 0);
            short8 bw2 = *(const short8*)(b2p + kk * 32);
            acc = __builtin_amdgcn_mfma_f32_16x16x32_bf16(a2[kk], bw2, acc, 0, 0, 0);
        }
        int col = c * 16 + m;
        float b = bias[col];
#pragma unroll
        for (int i = 0; i < 4; ++i) {
            int gn = nodeBase + kq * 4 + i;
            if (gn < n_nodes) {
                float v = acc[i] + b;
                v = (v > 0.f) ? v : expm1f(v);
                outb[(size_t)gn * 128 + col] = __float2bfloat16(v);
            }
        }
    }
}

// layer2 fused: mu = mean2@Wmu_rel^T + bmu + h@Wmu_root^T ; lv likewise. fp32 out.
__global__ __launch_bounds__(256)
void linear2_mfma(const __hip_bfloat16* __restrict__ Ab1,  // mean2b [N,128]
                  const __hip_bfloat16* __restrict__ Ab2,  // hb [N,128]
                  const __hip_bfloat16* __restrict__ Wb,
                  const float* __restrict__ bmu, const float* __restrict__ blv,
                  float* __restrict__ out,                 // mu@0, lv@N*64
                  int n_nodes) {
    int wid  = threadIdx.x >> 6;
    int lane = threadIdx.x & 63;
    int nodeBase = blockIdx.x * 64 + wid * 16;
    int m  = lane & 15;
    int kq = lane >> 4;
    int node = nodeBase + m;
    int nodeC = (node < n_nodes) ? node : (n_nodes - 1);

    short8 a1[4], a2[4];
    const short* A1p = (const short*)Ab1 + (size_t)nodeC * 128 + kq * 8;
    const short* A2p = (const short*)Ab2 + (size_t)nodeC * 128 + kq * 8;
#pragma unroll
    for (int kk = 0; kk < 4; ++kk) {
        a1[kk] = *(const short8*)(A1p + kk * 32);
        a2[kk] = *(const short8*)(A2p + kk * 32);
    }
    const short* WmuR = (const short*)Wb + 32768;
    const short* WmuT = (const short*)Wb + 40960;
    const short* WlvR = (const short*)Wb + 49152;
    const short* WlvT = (const short*)Wb + 57344;

#pragma unroll
    for (int c = 0; c < 4; ++c) {
        f32x4 accMu = {0.f, 0.f, 0.f, 0.f};
        f32x4 accLv = {0.f, 0.f, 0.f, 0.f};
        size_t wrow = (size_t)(c * 16 + m) * 128 + kq * 8;
#pragma unroll
        for (int kk = 0; kk < 4; ++kk) {
            short8 bm1 = *(const short8*)(WmuR + wrow + kk * 32);
            accMu = __builtin_amdgcn_mfma_f32_16x16x32_bf16(a1[kk], bm1, accMu, 0, 0, 0);
            short8 bm2 = *(const short8*)(WmuT + wrow + kk * 32);
            accMu = __builtin_amdgcn_mfma_f32_16x16x32_bf16(a2[kk], bm2, accMu, 0, 0, 0);
            short8 bl1 = *(const short8*)(WlvR + wrow + kk * 32);
            accLv = __builtin_amdgcn_mfma_f32_16x16x32_bf16(a1[kk], bl1, accLv, 0, 0, 0);
            short8 bl2 = *(const short8*)(WlvT + wrow + kk * 32);
            accLv = __builtin_amdgcn_mfma_f32_16x16x32_bf16(a2[kk], bl2, accLv, 0, 0, 0);
        }
        int col = c * 16 + m;
        float bm = bmu[col], bl = blv[col];
#pragma unroll
        for (int i = 0; i < 4; ++i) {
            int gn = nodeBase + kq * 4 + i;
            if (gn < n_nodes) {
                out[(size_t)gn * 64 + col] = accMu[i] + bm;
                out[(size_t)NNODES * 64 + (size_t)gn * 64 + col] = accLv[i] + bl;
            }
        }
    }
}

extern "C" void kernel_launch(void* const* d_in, const int* in_sizes, int n_in,
                              void* d_out, int out_size, void* d_ws, size_t ws_size,
                              hipStream_t stream) {
    const float* x        = (const float*)d_in[0];
    const int*   eidx     = (const int*)d_in[1];
    const float* eattr    = (const float*)d_in[2];
    const float* W1_rel   = (const float*)d_in[3];
    const float* b1_rel   = (const float*)d_in[4];
    const float* W1_root  = (const float*)d_in[5];
    const float* Wmu_rel  = (const float*)d_in[6];
    const float* bmu_rel  = (const float*)d_in[7];
    const float* Wmu_root = (const float*)d_in[8];
    const float* Wlv_rel  = (const float*)d_in[9];
    const float* blv_rel  = (const float*)d_in[10];
    const float* Wlv_root = (const float*)d_in[11];
    float* out = (float*)d_out;

    const int N = NNODES, E = NEDGES;
    const int nb = (N + 1023) / 1024;   // 49
    const int* src = eidx;
    const int* dst = eidx + E;

    char* ws = (char*)d_ws;
    size_t off = 0;
    int* cnt    = (int*)(ws + off); off += (size_t)N * 4;
    int* cursor = (int*)(ws + off); off += (size_t)N * 4;
    int* offs   = (int*)(ws + off); off += (size_t)(N + 1) * 4;
    int* excl   = (int*)(ws + off); off += (size_t)N * 4;
    int* bsum   = (int*)(ws + off); off += 256;
    off = (off + 15) & ~(size_t)15;
    int*   srcs_sorted = (int*)(ws + off);   off += (size_t)E * 4;
    float* ews_sorted  = (float*)(ws + off); off += (size_t)E * 4;
    __hip_bfloat16* xb    = (__hip_bfloat16*)(ws + off); off += (size_t)N * 128 * 2;
    __hip_bfloat16* meanb = (__hip_bfloat16*)(ws + off); off += (size_t)N * 128 * 2;
    __hip_bfloat16* hb    = (__hip_bfloat16*)(ws + off); off += (size_t)N * 128 * 2;
    __hip_bfloat16* Wb    = (__hip_bfloat16*)(ws + off); off += 65536 * 2;

    hipMemsetAsync(cnt, 0, (size_t)N * 4, stream);
    hipMemsetAsync(cursor, 0, (size_t)N * 4, stream);

    // conversions (independent of CSR build)
    cvt_x_kernel<<<(N * 128 / 8 + 255) / 256, 256, 0, stream>>>(x, xb, N * 128 / 8);
    cvt_weights_kernel<<<256, 256, 0, stream>>>(W1_rel, W1_root, Wmu_rel, Wmu_root,
                                                Wlv_rel, Wlv_root, Wb);

    // CSR build
    count_kernel<<<(E + 255) / 256, 256, 0, stream>>>(dst, cnt, E);
    scan1_kernel<<<nb, 1024, 0, stream>>>(cnt, excl, bsum, N);
    scan2_kernel<<<1, 64, 0, stream>>>(bsum, nb);
    scan3_kernel<<<nb, 1024, 0, stream>>>(excl, bsum, offs, N, nb);
    fill_kernel<<<(E + 255) / 256, 256, 0, stream>>>(src, dst, eattr, offs, cursor,
                                                     srcs_sorted, ews_sorted, E);

    // pass 1: mean of xb
    gather_mean_kernel<<<(N * 64 + 255) / 256, 256, 0, stream>>>(
        (const unsigned int*)xb, offs, srcs_sorted, ews_sorted, (unsigned int*)meanb, N);
    // h = elu(linear)
    linear1_mfma<<<(N + 63) / 64, 256, 0, stream>>>(meanb, xb, Wb, b1_rel, hb, N);
    // pass 2: mean of hb (reuse meanb)
    gather_mean_kernel<<<(N * 64 + 255) / 256, 256, 0, stream>>>(
        (const unsigned int*)hb, offs, srcs_sorted, ews_sorted, (unsigned int*)meanb, N);
    // mu + logvar fused
    linear2_mfma<<<(N + 63) / 64, 256, 0, stream>>>(meanb, hb, Wb, bmu_rel, blv_rel, out, N);
}

// Round 4
// 266.885 us; speedup vs baseline: 30.9909x; 1.3484x over previous
//
#include <hip/hip_runtime.h>
#include <hip/hip_bf16.h>
#include <math.h>

#define NNODES 50000
#define NEDGES 800000

using short8 = __attribute__((ext_vector_type(8))) short;
using f32x4  = __attribute__((ext_vector_type(4))) float;

__device__ __forceinline__ short f2bf(float f) {
    __hip_bfloat16 h = __float2bfloat16(f);
    return *reinterpret_cast<short*>(&h);
}

// ---------------- dtype conversion ----------------

__global__ __launch_bounds__(256)
void cvt_x_kernel(const float* __restrict__ in, __hip_bfloat16* __restrict__ out, int n8) {
    int i = blockIdx.x * 256 + threadIdx.x;
    if (i >= n8) return;
    const float4* p = (const float4*)in + (size_t)i * 2;
    float4 a = p[0], b = p[1];
    short8 o;
    o[0] = f2bf(a.x); o[1] = f2bf(a.y); o[2] = f2bf(a.z); o[3] = f2bf(a.w);
    o[4] = f2bf(b.x); o[5] = f2bf(b.y); o[6] = f2bf(b.z); o[7] = f2bf(b.w);
    *reinterpret_cast<short8*>((short*)out + (size_t)i * 8) = o;
}

// Wb layout (elems): W1_rel@0, W1_root@16384, Wmu_rel@32768, Wmu_root@40960,
//                    Wlv_rel@49152, Wlv_root@57344  (total 65536)
__global__ __launch_bounds__(256)
void cvt_weights_kernel(const float* __restrict__ w0, const float* __restrict__ w1,
                        const float* __restrict__ w2, const float* __restrict__ w3,
                        const float* __restrict__ w4, const float* __restrict__ w5,
                        __hip_bfloat16* __restrict__ out) {
    int i = blockIdx.x * 256 + threadIdx.x;   // 256 blocks -> 65536
    const float* src; int off;
    if      (i < 16384) { src = w0; off = 0; }
    else if (i < 32768) { src = w1; off = 16384; }
    else if (i < 40960) { src = w2; off = 32768; }
    else if (i < 49152) { src = w3; off = 40960; }
    else if (i < 57344) { src = w4; off = 49152; }
    else                { src = w5; off = 57344; }
    out[i] = __float2bfloat16(src[i - off]);
}

// ---------------- CSR build ----------------

__global__ __launch_bounds__(256)
void count_kernel(const int* __restrict__ dst, int* __restrict__ cnt, int E) {
    int e = blockIdx.x * 256 + threadIdx.x;
    if (e < E) atomicAdd(&cnt[dst[e]], 1);
}

// hierarchical scan: per-block inclusive scan -> excl + block sums
__global__ __launch_bounds__(1024)
void scan1_kernel(const int* __restrict__ cnt, int* __restrict__ excl,
                  int* __restrict__ bsum, int n) {
    __shared__ int sdata[1024];
    int tid = threadIdx.x;
    int i = blockIdx.x * 1024 + tid;
    int v = (i < n) ? cnt[i] : 0;
    sdata[tid] = v;
    __syncthreads();
    for (int off = 1; off < 1024; off <<= 1) {
        int t = (tid >= off) ? sdata[tid - off] : 0;
        __syncthreads();
        sdata[tid] += t;
        __syncthreads();
    }
    if (i < n) excl[i] = sdata[tid] - v;
    if (tid == 1023) bsum[blockIdx.x] = sdata[1023];
}

__global__ void scan2_kernel(int* __restrict__ bsum, int nb) {
    if (threadIdx.x == 0 && blockIdx.x == 0) {
        int c = 0;
        for (int b = 0; b < nb; ++b) { int t = bsum[b]; bsum[b] = c; c += t; }
        bsum[nb] = c;
    }
}

__global__ __launch_bounds__(1024)
void scan3_kernel(const int* __restrict__ excl, const int* __restrict__ bsum,
                  int* __restrict__ offs, int n, int nb) {
    int i = blockIdx.x * 1024 + threadIdx.x;
    if (i < n) offs[i] = excl[i] + bsum[i >> 10];
    if (i == 0) offs[n] = bsum[nb];
}

// edges packed as int2{src, ew_bits}: one 8B store here, one 8B load in gather.
__global__ __launch_bounds__(256)
void fill_kernel(const int* __restrict__ src, const int* __restrict__ dst,
                 const float* __restrict__ ew,
                 const int* __restrict__ offs, int* __restrict__ cursor,
                 int2* __restrict__ edges, int E) {
    int e = blockIdx.x * 256 + threadIdx.x;
    if (e < E) {
        int d = dst[e];
        int p = atomicAdd(&cursor[d], 1);
        edges[offs[d] + p] = make_int2(src[e], __float_as_int(ew[e]));
    }
}

// ---------------- scatter-mean as node-centric gather (bf16 features) ----------------
// one wave per node; lane owns 2 bf16 features (one uint). fp32 accumulate.
// 4-way unrolled edge loop: 4 independent feature-row loads in flight per wave
// (latency-bound fix; round-3 serial loop ran at 19% BW / 19% VALU).

__global__ __launch_bounds__(256)
void gather_mean_kernel(const unsigned int* __restrict__ Fb,   // [N,64] uints = [N,128] bf16
                        const int* __restrict__ offs,
                        const int2* __restrict__ edges,
                        unsigned int* __restrict__ outb,       // [N,64] uints
                        int n_nodes) {
    int wave = (blockIdx.x * blockDim.x + threadIdx.x) >> 6;
    int lane = threadIdx.x & 63;
    if (wave >= n_nodes) return;
    int beg = offs[wave], end = offs[wave + 1];

    float ax0 = 0.f, ay0 = 0.f, ax1 = 0.f, ay1 = 0.f;
    float ax2 = 0.f, ay2 = 0.f, ax3 = 0.f, ay3 = 0.f;
    int s = beg;
    for (; s + 4 <= end; s += 4) {
        int2 e0 = edges[s + 0];
        int2 e1 = edges[s + 1];
        int2 e2 = edges[s + 2];
        int2 e3 = edges[s + 3];
        unsigned int v0 = Fb[(size_t)e0.x * 64 + lane];
        unsigned int v1 = Fb[(size_t)e1.x * 64 + lane];
        unsigned int v2 = Fb[(size_t)e2.x * 64 + lane];
        unsigned int v3 = Fb[(size_t)e3.x * 64 + lane];
        float w0 = __int_as_float(e0.y), w1 = __int_as_float(e1.y);
        float w2 = __int_as_float(e2.y), w3 = __int_as_float(e3.y);
        ax0 += __uint_as_float(v0 << 16) * w0;  ay0 += __uint_as_float(v0 & 0xffff0000u) * w0;
        ax1 += __uint_as_float(v1 << 16) * w1;  ay1 += __uint_as_float(v1 & 0xffff0000u) * w1;
        ax2 += __uint_as_float(v2 << 16) * w2;  ay2 += __uint_as_float(v2 & 0xffff0000u) * w2;
        ax3 += __uint_as_float(v3 << 16) * w3;  ay3 += __uint_as_float(v3 & 0xffff0000u) * w3;
    }
    if (s + 2 <= end) {
        int2 e0 = edges[s + 0];
        int2 e1 = edges[s + 1];
        unsigned int v0 = Fb[(size_t)e0.x * 64 + lane];
        unsigned int v1 = Fb[(size_t)e1.x * 64 + lane];
        float w0 = __int_as_float(e0.y), w1 = __int_as_float(e1.y);
        ax0 += __uint_as_float(v0 << 16) * w0;  ay0 += __uint_as_float(v0 & 0xffff0000u) * w0;
        ax1 += __uint_as_float(v1 << 16) * w1;  ay1 += __uint_as_float(v1 & 0xffff0000u) * w1;
        s += 2;
    }
    if (s < end) {
        int2 e0 = edges[s];
        unsigned int v0 = Fb[(size_t)e0.x * 64 + lane];
        float w0 = __int_as_float(e0.y);
        ax0 += __uint_as_float(v0 << 16) * w0;  ay0 += __uint_as_float(v0 & 0xffff0000u) * w0;
    }
    float ax = (ax0 + ax1) + (ax2 + ax3);
    float ay = (ay0 + ay1) + (ay2 + ay3);
    float inv = 1.f / fmaxf((float)(end - beg), 1.f);
    unsigned int lo = (unsigned int)(unsigned short)f2bf(ax * inv);
    unsigned int hi = (unsigned int)(unsigned short)f2bf(ay * inv);
    outb[(size_t)wave * 64 + lane] = lo | (hi << 16);
}

// ---------------- MFMA linears ----------------
// mfma_f32_16x16x32_bf16: A lane layout row=l&15, k=8*(l>>4)+j ; B col=l&15, same k;
// C/D: col=lane&15, row=(lane>>4)*4+reg  [learn_hip m89].
// Block = 4 waves, 64 nodes; wave w -> nodes [base+16w, base+16w+16).

// layer1: h = elu(mean1 @ W1rel^T + b1 + x @ W1root^T), bf16 out
__global__ __launch_bounds__(256)
void linear1_mfma(const __hip_bfloat16* __restrict__ Ab1,  // mean1b [N,128]
                  const __hip_bfloat16* __restrict__ Ab2,  // xb [N,128]
                  const __hip_bfloat16* __restrict__ Wb,
                  const float* __restrict__ bias,          // [128]
                  __hip_bfloat16* __restrict__ outb,       // hb [N,128]
                  int n_nodes) {
    int wid  = threadIdx.x >> 6;
    int lane = threadIdx.x & 63;
    int nodeBase = blockIdx.x * 64 + wid * 16;
    int m  = lane & 15;
    int kq = lane >> 4;
    int node = nodeBase + m;
    int nodeC = (node < n_nodes) ? node : (n_nodes - 1);

    short8 a1[4], a2[4];
    const short* A1p = (const short*)Ab1 + (size_t)nodeC * 128 + kq * 8;
    const short* A2p = (const short*)Ab2 + (size_t)nodeC * 128 + kq * 8;
#pragma unroll
    for (int kk = 0; kk < 4; ++kk) {
        a1[kk] = *(const short8*)(A1p + kk * 32);
        a2[kk] = *(const short8*)(A2p + kk * 32);
    }
    const short* Wrel  = (const short*)Wb;           // W1_rel
    const short* Wroot = (const short*)Wb + 16384;   // W1_root

#pragma unroll
    for (int c = 0; c < 8; ++c) {
        f32x4 acc = {0.f, 0.f, 0.f, 0.f};
        const short* b1p = Wrel  + (size_t)(c * 16 + m) * 128 + kq * 8;
        const short* b2p = Wroot + (size_t)(c * 16 + m) * 128 + kq * 8;
#pragma unroll
        for (int kk = 0; kk < 4; ++kk) {
            short8 bw1 = *(const short8*)(b1p + kk * 32);
            acc = __builtin_amdgcn_mfma_f32_16x16x32_bf16(a1[kk], bw1, acc, 0, 0, 0);
            short8 bw2 = *(const short8*)(b2p + kk * 32);
            acc = __builtin_amdgcn_mfma_f32_16x16x32_bf16(a2[kk], bw2, acc, 0, 0, 0);
        }
        int col = c * 16 + m;
        float b = bias[col];
#pragma unroll
        for (int i = 0; i < 4; ++i) {
            int gn = nodeBase + kq * 4 + i;
            if (gn < n_nodes) {
                float v = acc[i] + b;
                v = (v > 0.f) ? v : expm1f(v);
                outb[(size_t)gn * 128 + col] = __float2bfloat16(v);
            }
        }
    }
}

// layer2 fused: mu = mean2@Wmu_rel^T + bmu + h@Wmu_root^T ; lv likewise. fp32 out.
__global__ __launch_bounds__(256)
void linear2_mfma(const __hip_bfloat16* __restrict__ Ab1,  // mean2b [N,128]
                  const __hip_bfloat16* __restrict__ Ab2,  // hb [N,128]
                  const __hip_bfloat16* __restrict__ Wb,
                  const float* __restrict__ bmu, const float* __restrict__ blv,
                  float* __restrict__ out,                 // mu@0, lv@N*64
                  int n_nodes) {
    int wid  = threadIdx.x >> 6;
    int lane = threadIdx.x & 63;
    int nodeBase = blockIdx.x * 64 + wid * 16;
    int m  = lane & 15;
    int kq = lane >> 4;
    int node = nodeBase + m;
    int nodeC = (node < n_nodes) ? node : (n_nodes - 1);

    short8 a1[4], a2[4];
    const short* A1p = (const short*)Ab1 + (size_t)nodeC * 128 + kq * 8;
    const short* A2p = (const short*)Ab2 + (size_t)nodeC * 128 + kq * 8;
#pragma unroll
    for (int kk = 0; kk < 4; ++kk) {
        a1[kk] = *(const short8*)(A1p + kk * 32);
        a2[kk] = *(const short8*)(A2p + kk * 32);
    }
    const short* WmuR = (const short*)Wb + 32768;
    const short* WmuT = (const short*)Wb + 40960;
    const short* WlvR = (const short*)Wb + 49152;
    const short* WlvT = (const short*)Wb + 57344;

#pragma unroll
    for (int c = 0; c < 4; ++c) {
        f32x4 accMu = {0.f, 0.f, 0.f, 0.f};
        f32x4 accLv = {0.f, 0.f, 0.f, 0.f};
        size_t wrow = (size_t)(c * 16 + m) * 128 + kq * 8;
#pragma unroll
        for (int kk = 0; kk < 4; ++kk) {
            short8 bm1 = *(const short8*)(WmuR + wrow + kk * 32);
            accMu = __builtin_amdgcn_mfma_f32_16x16x32_bf16(a1[kk], bm1, accMu, 0, 0, 0);
            short8 bm2 = *(const short8*)(WmuT + wrow + kk * 32);
            accMu = __builtin_amdgcn_mfma_f32_16x16x32_bf16(a2[kk], bm2, accMu, 0, 0, 0);
            short8 bl1 = *(const short8*)(WlvR + wrow + kk * 32);
            accLv = __builtin_amdgcn_mfma_f32_16x16x32_bf16(a1[kk], bl1, accLv, 0, 0, 0);
            short8 bl2 = *(const short8*)(WlvT + wrow + kk * 32);
            accLv = __builtin_amdgcn_mfma_f32_16x16x32_bf16(a2[kk], bl2, accLv, 0, 0, 0);
        }
        int col = c * 16 + m;
        float bm = bmu[col], bl = blv[col];
#pragma unroll
        for (int i = 0; i < 4; ++i) {
            int gn = nodeBase + kq * 4 + i;
            if (gn < n_nodes) {
                out[(size_t)gn * 64 + col] = accMu[i] + bm;
                out[(size_t)NNODES * 64 + (size_t)gn * 64 + col] = accLv[i] + bl;
            }
        }
    }
}

extern "C" void kernel_launch(void* const* d_in, const int* in_sizes, int n_in,
                              void* d_out, int out_size, void* d_ws, size_t ws_size,
                              hipStream_t stream) {
    const float* x        = (const float*)d_in[0];
    const int*   eidx     = (const int*)d_in[1];
    const float* eattr    = (const float*)d_in[2];
    const float* W1_rel   = (const float*)d_in[3];
    const float* b1_rel   = (const float*)d_in[4];
    const float* W1_root  = (const float*)d_in[5];
    const float* Wmu_rel  = (const float*)d_in[6];
    const float* bmu_rel  = (const float*)d_in[7];
    const float* Wmu_root = (const float*)d_in[8];
    const float* Wlv_rel  = (const float*)d_in[9];
    const float* blv_rel  = (const float*)d_in[10];
    const float* Wlv_root = (const float*)d_in[11];
    float* out = (float*)d_out;

    const int N = NNODES, E = NEDGES;
    const int nb = (N + 1023) / 1024;   // 49
    const int* src = eidx;
    const int* dst = eidx + E;

    char* ws = (char*)d_ws;
    size_t off = 0;
    int* cnt    = (int*)(ws + off); off += (size_t)N * 4;
    int* cursor = (int*)(ws + off); off += (size_t)N * 4;
    int* offs   = (int*)(ws + off); off += (size_t)(N + 1) * 4;
    int* excl   = (int*)(ws + off); off += (size_t)N * 4;
    int* bsum   = (int*)(ws + off); off += 256;
    off = (off + 15) & ~(size_t)15;
    int2* edges = (int2*)(ws + off); off += (size_t)E * 8;
    __hip_bfloat16* xb    = (__hip_bfloat16*)(ws + off); off += (size_t)N * 128 * 2;
    __hip_bfloat16* meanb = (__hip_bfloat16*)(ws + off); off += (size_t)N * 128 * 2;
    __hip_bfloat16* hb    = (__hip_bfloat16*)(ws + off); off += (size_t)N * 128 * 2;
    __hip_bfloat16* Wb    = (__hip_bfloat16*)(ws + off); off += 65536 * 2;

    hipMemsetAsync(cnt, 0, (size_t)N * 4, stream);
    hipMemsetAsync(cursor, 0, (size_t)N * 4, stream);

    // conversions (independent of CSR build)
    cvt_x_kernel<<<(N * 128 / 8 + 255) / 256, 256, 0, stream>>>(x, xb, N * 128 / 8);
    cvt_weights_kernel<<<256, 256, 0, stream>>>(W1_rel, W1_root, Wmu_rel, Wmu_root,
                                                Wlv_rel, Wlv_root, Wb);

    // CSR build
    count_kernel<<<(E + 255) / 256, 256, 0, stream>>>(dst, cnt, E);
    scan1_kernel<<<nb, 1024, 0, stream>>>(cnt, excl, bsum, N);
    scan2_kernel<<<1, 64, 0, stream>>>(bsum, nb);
    scan3_kernel<<<nb, 1024, 0, stream>>>(excl, bsum, offs, N, nb);
    fill_kernel<<<(E + 255) / 256, 256, 0, stream>>>(src, dst, eattr, offs, cursor, edges, E);

    // pass 1: mean of xb
    gather_mean_kernel<<<(N * 64 + 255) / 256, 256, 0, stream>>>(
        (const unsigned int*)xb, offs, edges, (unsigned int*)meanb, N);
    // h = elu(linear)
    linear1_mfma<<<(N + 63) / 64, 256, 0, stream>>>(meanb, xb, Wb, b1_rel, hb, N);
    // pass 2: mean of hb (reuse meanb)
    gather_mean_kernel<<<(N * 64 + 255) / 256, 256, 0, stream>>>(
        (const unsigned int*)hb, offs, edges, (unsigned int*)meanb, N);
    // mu + logvar fused
    linear2_mfma<<<(N + 63) / 64, 256, 0, stream>>>(meanb, hb, Wb, bmu_rel, blv_rel, out, N);
}

// Round 5
// 255.923 us; speedup vs baseline: 32.3182x; 1.0428x over previous
//
#include <hip/hip_runtime.h>
#include <hip/hip_bf16.h>
#include <math.h>

#define NNODES 50000
#define NEDGES 800000

using short8 = __attribute__((ext_vector_type(8))) short;
using f32x4  = __attribute__((ext_vector_type(4))) float;
typedef unsigned long long u64;

__device__ __forceinline__ short f2bf(float f) {
    __hip_bfloat16 h = __float2bfloat16(f);
    return *reinterpret_cast<short*>(&h);
}

// ---------------- fused prep: cvt_x | cvt_weights | count ----------------
// grid partition: [0,3125) cvt_x, [3125,3381) cvt_w, [3381,6506) count.
// Wb layout (elems): W1_rel@0, W1_root@16384, Wmu_rel@32768, Wmu_root@40960,
//                    Wlv_rel@49152, Wlv_root@57344  (total 65536)

__global__ __launch_bounds__(256)
void prep_kernel(const float* __restrict__ x, __hip_bfloat16* __restrict__ xb,
                 const float* __restrict__ w0, const float* __restrict__ w1,
                 const float* __restrict__ w2, const float* __restrict__ w3,
                 const float* __restrict__ w4, const float* __restrict__ w5,
                 __hip_bfloat16* __restrict__ Wb,
                 const int* __restrict__ dst, int* __restrict__ cnt) {
    int b = blockIdx.x;
    int tid = threadIdx.x;
    if (b < 3125) {                       // cvt x: 800000 short8 items
        int i = b * 256 + tid;
        const float4* p = (const float4*)x + (size_t)i * 2;
        float4 a = p[0], c = p[1];
        short8 o;
        o[0] = f2bf(a.x); o[1] = f2bf(a.y); o[2] = f2bf(a.z); o[3] = f2bf(a.w);
        o[4] = f2bf(c.x); o[5] = f2bf(c.y); o[6] = f2bf(c.z); o[7] = f2bf(c.w);
        *reinterpret_cast<short8*>((short*)xb + (size_t)i * 8) = o;
    } else if (b < 3381) {                // cvt weights: 65536 elems
        int i = (b - 3125) * 256 + tid;
        const float* src; int off;
        if      (i < 16384) { src = w0; off = 0; }
        else if (i < 32768) { src = w1; off = 16384; }
        else if (i < 40960) { src = w2; off = 32768; }
        else if (i < 49152) { src = w3; off = 40960; }
        else if (i < 57344) { src = w4; off = 49152; }
        else                { src = w5; off = 57344; }
        Wb[i] = __float2bfloat16(src[i - off]);
    } else {                              // count: E edges
        int e = (b - 3381) * 256 + tid;
        if (e < NEDGES) atomicAdd(&cnt[dst[e]], 1);
    }
}

// ---------------- hierarchical scan ----------------

__global__ __launch_bounds__(1024)
void scan1_kernel(const int* __restrict__ cnt, int* __restrict__ excl,
                  int* __restrict__ bsum, int n) {
    __shared__ int sdata[1024];
    int tid = threadIdx.x;
    int i = blockIdx.x * 1024 + tid;
    int v = (i < n) ? cnt[i] : 0;
    sdata[tid] = v;
    __syncthreads();
    for (int off = 1; off < 1024; off <<= 1) {
        int t = (tid >= off) ? sdata[tid - off] : 0;
        __syncthreads();
        sdata[tid] += t;
        __syncthreads();
    }
    if (i < n) excl[i] = sdata[tid] - v;
    if (tid == 1023) bsum[blockIdx.x] = sdata[1023];
}

// single-wave shfl scan over nb (<=64) block sums
__global__ __launch_bounds__(64)
void scan2_kernel(int* __restrict__ bsum, int nb) {
    int lane = threadIdx.x;
    int v = (lane < nb) ? bsum[lane] : 0;
    int incl = v;
    for (int off = 1; off < 64; off <<= 1) {
        int t = __shfl_up(incl, off);
        if (lane >= off) incl += t;
    }
    if (lane < nb) bsum[lane] = incl - v;   // exclusive
    if (lane == 63) bsum[nb] = incl;        // total
}

// ---------------- fill: scatter edges into CSR order ----------------
// slot cursor = atomicSub on cnt itself (cnt consumed); offs computed inline.
// nontemporal 8B store: avoid write-allocate line amplification (r4: 52MB HBM
// writes = E*64B full-line writebacks for a 6.4MB payload).

__global__ __launch_bounds__(256)
void fill_kernel(const int* __restrict__ src, const int* __restrict__ dst,
                 const float* __restrict__ ew,
                 const int* __restrict__ excl, const int* __restrict__ bsum,
                 int* __restrict__ cnt, u64* __restrict__ edges, int E) {
    int e = blockIdx.x * 256 + threadIdx.x;
    if (e < E) {
        int d = dst[e];
        int p = atomicSub(&cnt[d], 1);                 // old value; 1-based index
        int slot = excl[d] + bsum[d >> 10] + p - 1;
        u64 pack = ((u64)(unsigned int)__float_as_int(ew[e]) << 32) | (unsigned int)src[e];
        __builtin_nontemporal_store(pack, edges + slot);
    }
}

// ---------------- scatter-mean as node-centric gather (bf16 features) ----------------
// one wave per node; lane owns 2 bf16 features (one uint). fp32 accumulate.
// 8 independent accumulator chains -> 8 feature-row loads in flight per wave.

__device__ __forceinline__ void gstep(u64 e, const unsigned int* __restrict__ Fb,
                                      int lane, float& ax, float& ay) {
    unsigned int v = Fb[(size_t)(unsigned int)e * 64 + lane];
    float w = __uint_as_float((unsigned int)(e >> 32));
    ax += __uint_as_float(v << 16) * w;
    ay += __uint_as_float(v & 0xffff0000u) * w;
}

__global__ __launch_bounds__(256)
void gather_mean_kernel(const unsigned int* __restrict__ Fb,   // [N,64] uints = [N,128] bf16
                        const int* __restrict__ excl, const int* __restrict__ bsum,
                        const u64* __restrict__ edges,
                        unsigned int* __restrict__ outb,       // [N,64] uints
                        int n_nodes, int E) {
    int node = (blockIdx.x * blockDim.x + threadIdx.x) >> 6;
    int lane = threadIdx.x & 63;
    if (node >= n_nodes) return;
    int beg = excl[node] + bsum[node >> 10];
    int end = (node + 1 < n_nodes) ? (excl[node + 1] + bsum[(node + 1) >> 10]) : E;

    float ax[8], ay[8];
#pragma unroll
    for (int j = 0; j < 8; ++j) { ax[j] = 0.f; ay[j] = 0.f; }

    int s = beg;
    for (; s + 8 <= end; s += 8) {
        u64 e[8];
#pragma unroll
        for (int j = 0; j < 8; ++j) e[j] = __builtin_nontemporal_load(edges + s + j);
#pragma unroll
        for (int j = 0; j < 8; ++j) gstep(e[j], Fb, lane, ax[j], ay[j]);
    }
    if (s + 4 <= end) {
        u64 e[4];
#pragma unroll
        for (int j = 0; j < 4; ++j) e[j] = __builtin_nontemporal_load(edges + s + j);
#pragma unroll
        for (int j = 0; j < 4; ++j) gstep(e[j], Fb, lane, ax[j], ay[j]);
        s += 4;
    }
    if (s + 2 <= end) {
        u64 e0 = __builtin_nontemporal_load(edges + s);
        u64 e1 = __builtin_nontemporal_load(edges + s + 1);
        gstep(e0, Fb, lane, ax[0], ay[0]);
        gstep(e1, Fb, lane, ax[1], ay[1]);
        s += 2;
    }
    if (s < end) {
        u64 e0 = __builtin_nontemporal_load(edges + s);
        gstep(e0, Fb, lane, ax[0], ay[0]);
    }
#pragma unroll
    for (int j = 4; j < 8; ++j) { ax[j - 4] += ax[j]; ay[j - 4] += ay[j]; }
    float axs = (ax[0] + ax[1]) + (ax[2] + ax[3]);
    float ays = (ay[0] + ay[1]) + (ay[2] + ay[3]);
    float inv = 1.f / fmaxf((float)(end - beg), 1.f);
    unsigned int lo = (unsigned int)(unsigned short)f2bf(axs * inv);
    unsigned int hi = (unsigned int)(unsigned short)f2bf(ays * inv);
    outb[(size_t)node * 64 + lane] = lo | (hi << 16);
}

// ---------------- MFMA linears ----------------
// mfma_f32_16x16x32_bf16: A row=l&15, k=8*(l>>4)+j ; B col=l&15; C/D col=lane&15,
// row=(lane>>4)*4+reg [learn_hip m89]. Block = 4 waves, 64 nodes.

__global__ __launch_bounds__(256)
void linear1_mfma(const __hip_bfloat16* __restrict__ Ab1,  // mean1b [N,128]
                  const __hip_bfloat16* __restrict__ Ab2,  // xb [N,128]
                  const __hip_bfloat16* __restrict__ Wb,
                  const float* __restrict__ bias,          // [128]
                  __hip_bfloat16* __restrict__ outb,       // hb [N,128]
                  int n_nodes) {
    int wid  = threadIdx.x >> 6;
    int lane = threadIdx.x & 63;
    int nodeBase = blockIdx.x * 64 + wid * 16;
    int m  = lane & 15;
    int kq = lane >> 4;
    int node = nodeBase + m;
    int nodeC = (node < n_nodes) ? node : (n_nodes - 1);

    short8 a1[4], a2[4];
    const short* A1p = (const short*)Ab1 + (size_t)nodeC * 128 + kq * 8;
    const short* A2p = (const short*)Ab2 + (size_t)nodeC * 128 + kq * 8;
#pragma unroll
    for (int kk = 0; kk < 4; ++kk) {
        a1[kk] = *(const short8*)(A1p + kk * 32);
        a2[kk] = *(const short8*)(A2p + kk * 32);
    }
    const short* Wrel  = (const short*)Wb;           // W1_rel
    const short* Wroot = (const short*)Wb + 16384;   // W1_root

#pragma unroll
    for (int c = 0; c < 8; ++c) {
        f32x4 acc = {0.f, 0.f, 0.f, 0.f};
        const short* b1p = Wrel  + (size_t)(c * 16 + m) * 128 + kq * 8;
        const short* b2p = Wroot + (size_t)(c * 16 + m) * 128 + kq * 8;
#pragma unroll
        for (int kk = 0; kk < 4; ++kk) {
            short8 bw1 = *(const short8*)(b1p + kk * 32);
            acc = __builtin_amdgcn_mfma_f32_16x16x32_bf16(a1[kk], bw1, acc, 0, 0, 0);
            short8 bw2 = *(const short8*)(b2p + kk * 32);
            acc = __builtin_amdgcn_mfma_f32_16x16x32_bf16(a2[kk], bw2, acc, 0, 0, 0);
        }
        int col = c * 16 + m;
        float b = bias[col];
#pragma unroll
        for (int i = 0; i < 4; ++i) {
            int gn = nodeBase + kq * 4 + i;
            if (gn < n_nodes) {
                float v = acc[i] + b;
                v = (v > 0.f) ? v : expm1f(v);
                outb[(size_t)gn * 128 + col] = __float2bfloat16(v);
            }
        }
    }
}

__global__ __launch_bounds__(256)
void linear2_mfma(const __hip_bfloat16* __restrict__ Ab1,  // mean2b [N,128]
                  const __hip_bfloat16* __restrict__ Ab2,  // hb [N,128]
                  const __hip_bfloat16* __restrict__ Wb,
                  const float* __restrict__ bmu, const float* __restrict__ blv,
                  float* __restrict__ out,                 // mu@0, lv@N*64
                  int n_nodes) {
    int wid  = threadIdx.x >> 6;
    int lane = threadIdx.x & 63;
    int nodeBase = blockIdx.x * 64 + wid * 16;
    int m  = lane & 15;
    int kq = lane >> 4;
    int node = nodeBase + m;
    int nodeC = (node < n_nodes) ? node : (n_nodes - 1);

    short8 a1[4], a2[4];
    const short* A1p = (const short*)Ab1 + (size_t)nodeC * 128 + kq * 8;
    const short* A2p = (const short*)Ab2 + (size_t)nodeC * 128 + kq * 8;
#pragma unroll
    for (int kk = 0; kk < 4; ++kk) {
        a1[kk] = *(const short8*)(A1p + kk * 32);
        a2[kk] = *(const short8*)(A2p + kk * 32);
    }
    const short* WmuR = (const short*)Wb + 32768;
    const short* WmuT = (const short*)Wb + 40960;
    const short* WlvR = (const short*)Wb + 49152;
    const short* WlvT = (const short*)Wb + 57344;

#pragma unroll
    for (int c = 0; c < 4; ++c) {
        f32x4 accMu = {0.f, 0.f, 0.f, 0.f};
        f32x4 accLv = {0.f, 0.f, 0.f, 0.f};
        size_t wrow = (size_t)(c * 16 + m) * 128 + kq * 8;
#pragma unroll
        for (int kk = 0; kk < 4; ++kk) {
            short8 bm1 = *(const short8*)(WmuR + wrow + kk * 32);
            accMu = __builtin_amdgcn_mfma_f32_16x16x32_bf16(a1[kk], bm1, accMu, 0, 0, 0);
            short8 bm2 = *(const short8*)(WmuT + wrow + kk * 32);
            accMu = __builtin_amdgcn_mfma_f32_16x16x32_bf16(a2[kk], bm2, accMu, 0, 0, 0);
            short8 bl1 = *(const short8*)(WlvR + wrow + kk * 32);
            accLv = __builtin_amdgcn_mfma_f32_16x16x32_bf16(a1[kk], bl1, accLv, 0, 0, 0);
            short8 bl2 = *(const short8*)(WlvT + wrow + kk * 32);
            accLv = __builtin_amdgcn_mfma_f32_16x16x32_bf16(a2[kk], bl2, accLv, 0, 0, 0);
        }
        int col = c * 16 + m;
        float bm = bmu[col], bl = blv[col];
#pragma unroll
        for (int i = 0; i < 4; ++i) {
            int gn = nodeBase + kq * 4 + i;
            if (gn < n_nodes) {
                out[(size_t)gn * 64 + col] = accMu[i] + bm;
                out[(size_t)NNODES * 64 + (size_t)gn * 64 + col] = accLv[i] + bl;
            }
        }
    }
}

extern "C" void kernel_launch(void* const* d_in, const int* in_sizes, int n_in,
                              void* d_out, int out_size, void* d_ws, size_t ws_size,
                              hipStream_t stream) {
    const float* x        = (const float*)d_in[0];
    const int*   eidx     = (const int*)d_in[1];
    const float* eattr    = (const float*)d_in[2];
    const float* W1_rel   = (const float*)d_in[3];
    const float* b1_rel   = (const float*)d_in[4];
    const float* W1_root  = (const float*)d_in[5];
    const float* Wmu_rel  = (const float*)d_in[6];
    const float* bmu_rel  = (const float*)d_in[7];
    const float* Wmu_root = (const float*)d_in[8];
    const float* Wlv_rel  = (const float*)d_in[9];
    const float* blv_rel  = (const float*)d_in[10];
    const float* Wlv_root = (const float*)d_in[11];
    float* out = (float*)d_out;

    const int N = NNODES, E = NEDGES;
    const int nb = (N + 1023) / 1024;   // 49
    const int* src = eidx;
    const int* dst = eidx + E;

    char* ws = (char*)d_ws;
    size_t off = 0;
    int* cnt  = (int*)(ws + off); off += (size_t)N * 4;
    int* excl = (int*)(ws + off); off += (size_t)N * 4;
    int* bsum = (int*)(ws + off); off += 256;
    off = (off + 15) & ~(size_t)15;
    u64* edges = (u64*)(ws + off); off += (size_t)E * 8;
    __hip_bfloat16* xb    = (__hip_bfloat16*)(ws + off); off += (size_t)N * 128 * 2;
    __hip_bfloat16* meanb = (__hip_bfloat16*)(ws + off); off += (size_t)N * 128 * 2;
    __hip_bfloat16* hb    = (__hip_bfloat16*)(ws + off); off += (size_t)N * 128 * 2;
    __hip_bfloat16* Wb    = (__hip_bfloat16*)(ws + off); off += 65536 * 2;

    hipMemsetAsync(cnt, 0, (size_t)N * 4, stream);

    // prep: cvt_x | cvt_weights | count  (grid-partitioned)
    prep_kernel<<<6506, 256, 0, stream>>>(x, xb, W1_rel, W1_root, Wmu_rel, Wmu_root,
                                          Wlv_rel, Wlv_root, Wb, dst, cnt);
    scan1_kernel<<<nb, 1024, 0, stream>>>(cnt, excl, bsum, N);
    scan2_kernel<<<1, 64, 0, stream>>>(bsum, nb);
    fill_kernel<<<(E + 255) / 256, 256, 0, stream>>>(src, dst, eattr, excl, bsum, cnt, edges, E);

    // pass 1: mean of xb
    gather_mean_kernel<<<(N * 64 + 255) / 256, 256, 0, stream>>>(
        (const unsigned int*)xb, excl, bsum, edges, (unsigned int*)meanb, N, E);
    // h = elu(linear)
    linear1_mfma<<<(N + 63) / 64, 256, 0, stream>>>(meanb, xb, Wb, b1_rel, hb, N);
    // pass 2: mean of hb (reuse meanb)
    gather_mean_kernel<<<(N * 64 + 255) / 256, 256, 0, stream>>>(
        (const unsigned int*)hb, excl, bsum, edges, (unsigned int*)meanb, N, E);
    // mu + logvar fused
    linear2_mfma<<<(N + 63) / 64, 256, 0, stream>>>(meanb, hb, Wb, bmu_rel, blv_rel, out, N);
}

// Round 6
// 241.967 us; speedup vs baseline: 34.1823x; 1.0577x over previous
//
#include <hip/hip_runtime.h>
#include <hip/hip_bf16.h>
#include <math.h>

#define NNODES 50000
#define NEDGES 800000
#define NRANGE 6250          // NNODES / 8 (exact)
#define CHUNK  2048
#define NCHUNK ((NEDGES + CHUNK - 1) / CHUNK)   // 391

using short8 = __attribute__((ext_vector_type(8))) short;
using f32x4  = __attribute__((ext_vector_type(4))) float;
typedef unsigned long long u64;

__device__ __forceinline__ short f2bf(float f) {
    __hip_bfloat16 h = __float2bfloat16(f);
    return *reinterpret_cast<short*>(&h);
}

// ---------------- fused prep: cvt_x | cvt_weights | count ----------------
// grid partition: [0,3125) cvt_x, [3125,3381) cvt_w, [3381,3381+NCHUNK*8) count.
// count is chunk x 8 partitioned: block handles chunk b2>>3, dst-range b2&7.
// With round-robin blockIdx->XCD this makes cnt[] atomics XCD-local (the r5
// lesson: cross-XCD partial-dirty lines write back once PER XCD -> 8x traffic).
// Wb layout (elems): W1_rel@0, W1_root@16384, Wmu_rel@32768, Wmu_root@40960,
//                    Wlv_rel@49152, Wlv_root@57344  (total 65536)

__global__ __launch_bounds__(256)
void prep_kernel(const float* __restrict__ x, __hip_bfloat16* __restrict__ xb,
                 const float* __restrict__ w0, const float* __restrict__ w1,
                 const float* __restrict__ w2, const float* __restrict__ w3,
                 const float* __restrict__ w4, const float* __restrict__ w5,
                 __hip_bfloat16* __restrict__ Wb,
                 const int* __restrict__ dst, int* __restrict__ cnt) {
    int b = blockIdx.x;
    int tid = threadIdx.x;
    if (b < 3125) {                       // cvt x: 800000 short8 items
        int i = b * 256 + tid;
        const float4* p = (const float4*)x + (size_t)i * 2;
        float4 a = p[0], c = p[1];
        short8 o;
        o[0] = f2bf(a.x); o[1] = f2bf(a.y); o[2] = f2bf(a.z); o[3] = f2bf(a.w);
        o[4] = f2bf(c.x); o[5] = f2bf(c.y); o[6] = f2bf(c.z); o[7] = f2bf(c.w);
        *reinterpret_cast<short8*>((short*)xb + (size_t)i * 8) = o;
    } else if (b < 3381) {                // cvt weights: 65536 elems
        int i = (b - 3125) * 256 + tid;
        const float* src; int off;
        if      (i < 16384) { src = w0; off = 0; }
        else if (i < 32768) { src = w1; off = 16384; }
        else if (i < 40960) { src = w2; off = 32768; }
        else if (i < 49152) { src = w3; off = 40960; }
        else if (i < 57344) { src = w4; off = 49152; }
        else                { src = w5; off = 57344; }
        Wb[i] = __float2bfloat16(src[i - off]);
    } else {                              // count: chunk x 8 partitioned
        int b2 = b - 3381;
        int chunk = b2 >> 3;
        int r = b2 & 7;
        int lo = r * NRANGE, hi = lo + NRANGE;
        int base = chunk * CHUNK;
        int end = min(base + CHUNK, NEDGES);
        for (int e = base + tid; e < end; e += 256) {
            int d = dst[e];
            if (d >= lo && d < hi) atomicAdd(&cnt[d], 1);
        }
    }
}

// ---------------- hierarchical scan ----------------

__global__ __launch_bounds__(1024)
void scan1_kernel(const int* __restrict__ cnt, int* __restrict__ excl,
                  int* __restrict__ bsum, int n) {
    __shared__ int sdata[1024];
    int tid = threadIdx.x;
    int i = blockIdx.x * 1024 + tid;
    int v = (i < n) ? cnt[i] : 0;
    sdata[tid] = v;
    __syncthreads();
    for (int off = 1; off < 1024; off <<= 1) {
        int t = (tid >= off) ? sdata[tid - off] : 0;
        __syncthreads();
        sdata[tid] += t;
        __syncthreads();
    }
    if (i < n) excl[i] = sdata[tid] - v;
    if (tid == 1023) bsum[blockIdx.x] = sdata[1023];
}

// single-wave shfl scan over nb (<=64) block sums
__global__ __launch_bounds__(64)
void scan2_kernel(int* __restrict__ bsum, int nb) {
    int lane = threadIdx.x;
    int v = (lane < nb) ? bsum[lane] : 0;
    int incl = v;
    for (int off = 1; off < 64; off <<= 1) {
        int t = __shfl_up(incl, off);
        if (lane >= off) incl += t;
    }
    if (lane < nb) bsum[lane] = incl - v;   // exclusive
    if (lane == 63) bsum[nb] = incl;        // total
}

// ---------------- fill: scatter edges into CSR order, XCD-partitioned ----------------
// block b: edge-chunk b>>3, dst-range b&7. All writes to slot-region r come
// from blocks b&7==r (one XCD under round-robin dispatch) -> single dirty L2
// copy per line -> writeback ~= payload (6.4MB), not 8x. Plain stores (r5:
// nontemporal did NOT avoid the amplification). Correct for ANY block->XCD
// mapping; only the traffic depends on it.

__global__ __launch_bounds__(256)
void fill_kernel(const int* __restrict__ src, const int* __restrict__ dst,
                 const float* __restrict__ ew,
                 const int* __restrict__ excl, const int* __restrict__ bsum,
                 int* __restrict__ cnt, u64* __restrict__ edges) {
    int b2 = blockIdx.x;
    int chunk = b2 >> 3;
    int r = b2 & 7;
    int lo = r * NRANGE, hi = lo + NRANGE;
    int base = chunk * CHUNK;
    int end = min(base + CHUNK, NEDGES);
    for (int e = base + threadIdx.x; e < end; e += 256) {
        int d = dst[e];
        if (d >= lo && d < hi) {
            int p = atomicSub(&cnt[d], 1);             // old value; 1-based
            int slot = excl[d] + bsum[d >> 10] + p - 1;
            u64 pack = ((u64)(unsigned int)__float_as_int(ew[e]) << 32) | (unsigned int)src[e];
            edges[slot] = pack;
        }
    }
}

// ---------------- scatter-mean as node-centric gather (bf16 features) ----------------
// one wave per node; lane owns 2 bf16 features (one uint). fp32 accumulate.
// 8 independent accumulator chains -> 8 feature-row loads in flight per wave.

__device__ __forceinline__ void gstep(u64 e, const unsigned int* __restrict__ Fb,
                                      int lane, float& ax, float& ay) {
    unsigned int v = Fb[(size_t)(unsigned int)e * 64 + lane];
    float w = __uint_as_float((unsigned int)(e >> 32));
    ax += __uint_as_float(v << 16) * w;
    ay += __uint_as_float(v & 0xffff0000u) * w;
}

__global__ __launch_bounds__(256)
void gather_mean_kernel(const unsigned int* __restrict__ Fb,   // [N,64] uints = [N,128] bf16
                        const int* __restrict__ excl, const int* __restrict__ bsum,
                        const u64* __restrict__ edges,
                        unsigned int* __restrict__ outb,       // [N,64] uints
                        int n_nodes, int E) {
    int node = (blockIdx.x * blockDim.x + threadIdx.x) >> 6;
    int lane = threadIdx.x & 63;
    if (node >= n_nodes) return;
    int beg = excl[node] + bsum[node >> 10];
    int end = (node + 1 < n_nodes) ? (excl[node + 1] + bsum[(node + 1) >> 10]) : E;

    float ax[8], ay[8];
#pragma unroll
    for (int j = 0; j < 8; ++j) { ax[j] = 0.f; ay[j] = 0.f; }

    int s = beg;
    for (; s + 8 <= end; s += 8) {
        u64 e[8];
#pragma unroll
        for (int j = 0; j < 8; ++j) e[j] = __builtin_nontemporal_load(edges + s + j);
#pragma unroll
        for (int j = 0; j < 8; ++j) gstep(e[j], Fb, lane, ax[j], ay[j]);
    }
    if (s + 4 <= end) {
        u64 e[4];
#pragma unroll
        for (int j = 0; j < 4; ++j) e[j] = __builtin_nontemporal_load(edges + s + j);
#pragma unroll
        for (int j = 0; j < 4; ++j) gstep(e[j], Fb, lane, ax[j], ay[j]);
        s += 4;
    }
    if (s + 2 <= end) {
        u64 e0 = __builtin_nontemporal_load(edges + s);
        u64 e1 = __builtin_nontemporal_load(edges + s + 1);
        gstep(e0, Fb, lane, ax[0], ay[0]);
        gstep(e1, Fb, lane, ax[1], ay[1]);
        s += 2;
    }
    if (s < end) {
        u64 e0 = __builtin_nontemporal_load(edges + s);
        gstep(e0, Fb, lane, ax[0], ay[0]);
    }
#pragma unroll
    for (int j = 4; j < 8; ++j) { ax[j - 4] += ax[j]; ay[j - 4] += ay[j]; }
    float axs = (ax[0] + ax[1]) + (ax[2] + ax[3]);
    float ays = (ay[0] + ay[1]) + (ay[2] + ay[3]);
    float inv = 1.f / fmaxf((float)(end - beg), 1.f);
    unsigned int lo = (unsigned int)(unsigned short)f2bf(axs * inv);
    unsigned int hi = (unsigned int)(unsigned short)f2bf(ays * inv);
    outb[(size_t)node * 64 + lane] = lo | (hi << 16);
}

// ---------------- MFMA linears ----------------
// mfma_f32_16x16x32_bf16: A row=l&15, k=8*(l>>4)+j ; B col=l&15; C/D col=lane&15,
// row=(lane>>4)*4+reg [learn_hip m89]. Block = 4 waves, 64 nodes.

__global__ __launch_bounds__(256)
void linear1_mfma(const __hip_bfloat16* __restrict__ Ab1,  // mean1b [N,128]
                  const __hip_bfloat16* __restrict__ Ab2,  // xb [N,128]
                  const __hip_bfloat16* __restrict__ Wb,
                  const float* __restrict__ bias,          // [128]
                  __hip_bfloat16* __restrict__ outb,       // hb [N,128]
                  int n_nodes) {
    int wid  = threadIdx.x >> 6;
    int lane = threadIdx.x & 63;
    int nodeBase = blockIdx.x * 64 + wid * 16;
    int m  = lane & 15;
    int kq = lane >> 4;
    int node = nodeBase + m;
    int nodeC = (node < n_nodes) ? node : (n_nodes - 1);

    short8 a1[4], a2[4];
    const short* A1p = (const short*)Ab1 + (size_t)nodeC * 128 + kq * 8;
    const short* A2p = (const short*)Ab2 + (size_t)nodeC * 128 + kq * 8;
#pragma unroll
    for (int kk = 0; kk < 4; ++kk) {
        a1[kk] = *(const short8*)(A1p + kk * 32);
        a2[kk] = *(const short8*)(A2p + kk * 32);
    }
    const short* Wrel  = (const short*)Wb;           // W1_rel
    const short* Wroot = (const short*)Wb + 16384;   // W1_root

#pragma unroll
    for (int c = 0; c < 8; ++c) {
        f32x4 acc = {0.f, 0.f, 0.f, 0.f};
        const short* b1p = Wrel  + (size_t)(c * 16 + m) * 128 + kq * 8;
        const short* b2p = Wroot + (size_t)(c * 16 + m) * 128 + kq * 8;
#pragma unroll
        for (int kk = 0; kk < 4; ++kk) {
            short8 bw1 = *(const short8*)(b1p + kk * 32);
            acc = __builtin_amdgcn_mfma_f32_16x16x32_bf16(a1[kk], bw1, acc, 0, 0, 0);
            short8 bw2 = *(const short8*)(b2p + kk * 32);
            acc = __builtin_amdgcn_mfma_f32_16x16x32_bf16(a2[kk], bw2, acc, 0, 0, 0);
        }
        int col = c * 16 + m;
        float b = bias[col];
#pragma unroll
        for (int i = 0; i < 4; ++i) {
            int gn = nodeBase + kq * 4 + i;
            if (gn < n_nodes) {
                float v = acc[i] + b;
                v = (v > 0.f) ? v : expm1f(v);
                outb[(size_t)gn * 128 + col] = __float2bfloat16(v);
            }
        }
    }
}

__global__ __launch_bounds__(256)
void linear2_mfma(const __hip_bfloat16* __restrict__ Ab1,  // mean2b [N,128]
                  const __hip_bfloat16* __restrict__ Ab2,  // hb [N,128]
                  const __hip_bfloat16* __restrict__ Wb,
                  const float* __restrict__ bmu, const float* __restrict__ blv,
                  float* __restrict__ out,                 // mu@0, lv@N*64
                  int n_nodes) {
    int wid  = threadIdx.x >> 6;
    int lane = threadIdx.x & 63;
    int nodeBase = blockIdx.x * 64 + wid * 16;
    int m  = lane & 15;
    int kq = lane >> 4;
    int node = nodeBase + m;
    int nodeC = (node < n_nodes) ? node : (n_nodes - 1);

    short8 a1[4], a2[4];
    const short* A1p = (const short*)Ab1 + (size_t)nodeC * 128 + kq * 8;
    const short* A2p = (const short*)Ab2 + (size_t)nodeC * 128 + kq * 8;
#pragma unroll
    for (int kk = 0; kk < 4; ++kk) {
        a1[kk] = *(const short8*)(A1p + kk * 32);
        a2[kk] = *(const short8*)(A2p + kk * 32);
    }
    const short* WmuR = (const short*)Wb + 32768;
    const short* WmuT = (const short*)Wb + 40960;
    const short* WlvR = (const short*)Wb + 49152;
    const short* WlvT = (const short*)Wb + 57344;

#pragma unroll
    for (int c = 0; c < 4; ++c) {
        f32x4 accMu = {0.f, 0.f, 0.f, 0.f};
        f32x4 accLv = {0.f, 0.f, 0.f, 0.f};
        size_t wrow = (size_t)(c * 16 + m) * 128 + kq * 8;
#pragma unroll
        for (int kk = 0; kk < 4; ++kk) {
            short8 bm1 = *(const short8*)(WmuR + wrow + kk * 32);
            accMu = __builtin_amdgcn_mfma_f32_16x16x32_bf16(a1[kk], bm1, accMu, 0, 0, 0);
            short8 bm2 = *(const short8*)(WmuT + wrow + kk * 32);
            accMu = __builtin_amdgcn_mfma_f32_16x16x32_bf16(a2[kk], bm2, accMu, 0, 0, 0);
            short8 bl1 = *(const short8*)(WlvR + wrow + kk * 32);
            accLv = __builtin_amdgcn_mfma_f32_16x16x32_bf16(a1[kk], bl1, accLv, 0, 0, 0);
            short8 bl2 = *(const short8*)(WlvT + wrow + kk * 32);
            accLv = __builtin_amdgcn_mfma_f32_16x16x32_bf16(a2[kk], bl2, accLv, 0, 0, 0);
        }
        int col = c * 16 + m;
        float bm = bmu[col], bl = blv[col];
#pragma unroll
        for (int i = 0; i < 4; ++i) {
            int gn = nodeBase + kq * 4 + i;
            if (gn < n_nodes) {
                out[(size_t)gn * 64 + col] = accMu[i] + bm;
                out[(size_t)NNODES * 64 + (size_t)gn * 64 + col] = accLv[i] + bl;
            }
        }
    }
}

extern "C" void kernel_launch(void* const* d_in, const int* in_sizes, int n_in,
                              void* d_out, int out_size, void* d_ws, size_t ws_size,
                              hipStream_t stream) {
    const float* x        = (const float*)d_in[0];
    const int*   eidx     = (const int*)d_in[1];
    const float* eattr    = (const float*)d_in[2];
    const float* W1_rel   = (const float*)d_in[3];
    const float* b1_rel   = (const float*)d_in[4];
    const float* W1_root  = (const float*)d_in[5];
    const float* Wmu_rel  = (const float*)d_in[6];
    const float* bmu_rel  = (const float*)d_in[7];
    const float* Wmu_root = (const float*)d_in[8];
    const float* Wlv_rel  = (const float*)d_in[9];
    const float* blv_rel  = (const float*)d_in[10];
    const float* Wlv_root = (const float*)d_in[11];
    float* out = (float*)d_out;

    const int N = NNODES, E = NEDGES;
    const int nb = (N + 1023) / 1024;   // 49
    const int* src = eidx;
    const int* dst = eidx + E;

    char* ws = (char*)d_ws;
    size_t off = 0;
    int* cnt  = (int*)(ws + off); off += (size_t)N * 4;
    int* excl = (int*)(ws + off); off += (size_t)N * 4;
    int* bsum = (int*)(ws + off); off += 256;
    off = (off + 15) & ~(size_t)15;
    u64* edges = (u64*)(ws + off); off += (size_t)E * 8;
    __hip_bfloat16* xb    = (__hip_bfloat16*)(ws + off); off += (size_t)N * 128 * 2;
    __hip_bfloat16* meanb = (__hip_bfloat16*)(ws + off); off += (size_t)N * 128 * 2;
    __hip_bfloat16* hb    = (__hip_bfloat16*)(ws + off); off += (size_t)N * 128 * 2;
    __hip_bfloat16* Wb    = (__hip_bfloat16*)(ws + off); off += 65536 * 2;

    hipMemsetAsync(cnt, 0, (size_t)N * 4, stream);

    // prep: cvt_x | cvt_weights | count  (grid-partitioned; count chunk x 8)
    prep_kernel<<<3381 + NCHUNK * 8, 256, 0, stream>>>(
        x, xb, W1_rel, W1_root, Wmu_rel, Wmu_root, Wlv_rel, Wlv_root, Wb, dst, cnt);
    scan1_kernel<<<nb, 1024, 0, stream>>>(cnt, excl, bsum, N);
    scan2_kernel<<<1, 64, 0, stream>>>(bsum, nb);
    fill_kernel<<<NCHUNK * 8, 256, 0, stream>>>(src, dst, eattr, excl, bsum, cnt, edges);

    // pass 1: mean of xb
    gather_mean_kernel<<<(N * 64 + 255) / 256, 256, 0, stream>>>(
        (const unsigned int*)xb, excl, bsum, edges, (unsigned int*)meanb, N, E);
    // h = elu(linear)
    linear1_mfma<<<(N + 63) / 64, 256, 0, stream>>>(meanb, xb, Wb, b1_rel, hb, N);
    // pass 2: mean of hb (reuse meanb)
    gather_mean_kernel<<<(N * 64 + 255) / 256, 256, 0, stream>>>(
        (const unsigned int*)hb, excl, bsum, edges, (unsigned int*)meanb, N, E);
    // mu + logvar fused
    linear2_mfma<<<(N + 63) / 64, 256, 0, stream>>>(meanb, hb, Wb, bmu_rel, blv_rel, out, N);
}

// Round 7
// 235.577 us; speedup vs baseline: 35.1094x; 1.0271x over previous
//
#include <hip/hip_runtime.h>
#include <hip/hip_bf16.h>
#include <math.h>

#define NNODES 50000
#define NEDGES 800000
#define NRANGE 6250          // NNODES / 8 (exact)
#define NC     64            // edge chunks
#define CHUNK_E (NEDGES / NC)   // 12500 exact

using short8 = __attribute__((ext_vector_type(8))) short;
using f32x4  = __attribute__((ext_vector_type(4))) float;
typedef unsigned long long u64;

__device__ __forceinline__ short f2bf(float f) {
    __hip_bfloat16 h = __float2bfloat16(f);
    return *reinterpret_cast<short*>(&h);
}

// ---------------- prep: cvt_x | cvt_weights (no atomics, no LDS) ----------------
// Wb layout (elems): W1_rel@0, W1_root@16384, Wmu_rel@32768, Wmu_root@40960,
//                    Wlv_rel@49152, Wlv_root@57344  (total 65536)

__global__ __launch_bounds__(256)
void prep_kernel(const float* __restrict__ x, __hip_bfloat16* __restrict__ xb,
                 const float* __restrict__ w0, const float* __restrict__ w1,
                 const float* __restrict__ w2, const float* __restrict__ w3,
                 const float* __restrict__ w4, const float* __restrict__ w5,
                 __hip_bfloat16* __restrict__ Wb) {
    int b = blockIdx.x;
    int tid = threadIdx.x;
    if (b < 3125) {                       // cvt x: 800000 short8 items
        int i = b * 256 + tid;
        const float4* p = (const float4*)x + (size_t)i * 2;
        float4 a = p[0], c = p[1];
        short8 o;
        o[0] = f2bf(a.x); o[1] = f2bf(a.y); o[2] = f2bf(a.z); o[3] = f2bf(a.w);
        o[4] = f2bf(c.x); o[5] = f2bf(c.y); o[6] = f2bf(c.z); o[7] = f2bf(c.w);
        *reinterpret_cast<short8*>((short*)xb + (size_t)i * 8) = o;
    } else {                              // cvt weights: 65536 elems
        int i = (b - 3125) * 256 + tid;
        const float* src; int off;
        if      (i < 16384) { src = w0; off = 0; }
        else if (i < 32768) { src = w1; off = 16384; }
        else if (i < 40960) { src = w2; off = 32768; }
        else if (i < 49152) { src = w3; off = 40960; }
        else if (i < 57344) { src = w4; off = 49152; }
        else                { src = w5; off = 57344; }
        Wb[i] = __float2bfloat16(src[i - off]);
    }
}

// ---------------- hist: per-chunk LDS histogram, NO global atomics ----------------
// r6 lesson: global atomicAdd writes through to HBM (~32B each; 800K atomics
// showed up as +23MB WRITE_SIZE in prep). LDS histogram + block-owned dump
// instead. 4 u8 counts packed per u32 (per-chunk per-node count <= ~8).

__global__ __launch_bounds__(256)
void hist_kernel(const int* __restrict__ dst, unsigned int* __restrict__ partial) {
    __shared__ unsigned int hist[NNODES / 4];   // 12500 u32 = 50KB
    int c = blockIdx.x;
    int tid = threadIdx.x;
    for (int i = tid; i < NNODES / 4; i += 256) hist[i] = 0;
    __syncthreads();
    int base = c * CHUNK_E;
    for (int e = base + tid; e < base + CHUNK_E; e += 256) {
        int d = dst[e];
        atomicAdd(&hist[d >> 2], 1u << (8 * (d & 3)));
    }
    __syncthreads();
    unsigned int* outp = partial + (size_t)c * (NNODES / 4);
    for (int i = tid; i < NNODES / 4; i += 256) outp[i] = hist[i];
}

// ---------------- scan1: degrees from partials + per-chunk bases + block scan ----

__global__ __launch_bounds__(1024)
void scan1_kernel(const unsigned int* __restrict__ partial,
                  unsigned char* __restrict__ cbase,   // [N][NC] u8, 64B/node
                  int* __restrict__ excl, int* __restrict__ bsum) {
    __shared__ int sdata[1024];
    int tid = threadIdx.x;
    int n = blockIdx.x * 1024 + tid;
    int deg = 0;
    if (n < NNODES) {
        int sh = 8 * (n & 3);
        int idx = n >> 2;
        unsigned int packed = 0;
        unsigned int* cbout = (unsigned int*)(cbase + (size_t)n * NC);
#pragma unroll 4
        for (int c = 0; c < NC; ++c) {
            unsigned int w = partial[(size_t)c * (NNODES / 4) + idx];
            unsigned int cc = (w >> sh) & 0xffu;
            packed |= ((unsigned int)(deg & 0xff)) << (8 * (c & 3));   // excl base
            deg += (int)cc;
            if ((c & 3) == 3) { cbout[c >> 2] = packed; packed = 0; }
        }
    }
    sdata[tid] = deg;
    __syncthreads();
    for (int off = 1; off < 1024; off <<= 1) {
        int t = (tid >= off) ? sdata[tid - off] : 0;
        __syncthreads();
        sdata[tid] += t;
        __syncthreads();
    }
    if (n < NNODES) excl[n] = sdata[tid] - deg;
    if (tid == 1023) bsum[blockIdx.x] = sdata[1023];
}

// single-wave shfl scan over nb (<=64) block sums
__global__ __launch_bounds__(64)
void scan2_kernel(int* __restrict__ bsum, int nb) {
    int lane = threadIdx.x;
    int v = (lane < nb) ? bsum[lane] : 0;
    int incl = v;
    for (int off = 1; off < 64; off <<= 1) {
        int t = __shfl_up(incl, off);
        if (lane >= off) incl += t;
    }
    if (lane < nb) bsum[lane] = incl - v;   // exclusive
    if (lane == 63) bsum[nb] = incl;        // total
}

// ---------------- fill: LDS-ranked CSR scatter, XCD-partitioned, NO global atomics -
// block b: chunk c=b>>3, dst-range r=b&7. Rank within (chunk,node) via LDS
// u16-packed cursors. slot = excl[d]+bsum[d>>10]+cbase[d][c]+rank. All writes
// to slot-region r come from blocks b&7==r (one XCD under round-robin).

__global__ __launch_bounds__(256)
void fill_kernel(const int* __restrict__ src, const int* __restrict__ dst,
                 const float* __restrict__ ew,
                 const int* __restrict__ excl, const int* __restrict__ bsum,
                 const unsigned char* __restrict__ cbase,
                 u64* __restrict__ edges) {
    __shared__ unsigned int cur[NRANGE / 2];    // 3125 u32 = 6250 u16 cursors
    int b = blockIdx.x;
    int c = b >> 3, r = b & 7;
    int lo = r * NRANGE;
    int tid = threadIdx.x;
    for (int i = tid; i < NRANGE / 2; i += 256) cur[i] = 0;
    __syncthreads();
    int base = c * CHUNK_E;
    for (int e = base + tid; e < base + CHUNK_E; e += 256) {
        int d = dst[e];
        unsigned int dl = (unsigned int)(d - lo);
        if (dl < NRANGE) {
            int sh = 16 * (dl & 1);
            unsigned int old = atomicAdd(&cur[dl >> 1], 1u << sh);
            int rank = (int)((old >> sh) & 0xffffu);
            int slot = excl[d] + bsum[d >> 10] + (int)cbase[(size_t)d * NC + c] + rank;
            u64 pack = ((u64)(unsigned int)__float_as_int(ew[e]) << 32) | (unsigned int)src[e];
            edges[slot] = pack;
        }
    }
}

// ---------------- scatter-mean as node-centric gather (bf16 features) ----------------
// one wave per node; lane owns 2 bf16 features (one uint). fp32 accumulate.
// 8 independent accumulator chains -> 8 feature-row loads in flight per wave.

__device__ __forceinline__ void gstep(u64 e, const unsigned int* __restrict__ Fb,
                                      int lane, float& ax, float& ay) {
    unsigned int v = Fb[(size_t)(unsigned int)e * 64 + lane];
    float w = __uint_as_float((unsigned int)(e >> 32));
    ax += __uint_as_float(v << 16) * w;
    ay += __uint_as_float(v & 0xffff0000u) * w;
}

__global__ __launch_bounds__(256)
void gather_mean_kernel(const unsigned int* __restrict__ Fb,   // [N,64] uints = [N,128] bf16
                        const int* __restrict__ excl, const int* __restrict__ bsum,
                        const u64* __restrict__ edges,
                        unsigned int* __restrict__ outb,       // [N,64] uints
                        int n_nodes, int E) {
    int node = (blockIdx.x * blockDim.x + threadIdx.x) >> 6;
    int lane = threadIdx.x & 63;
    if (node >= n_nodes) return;
    int beg = excl[node] + bsum[node >> 10];
    int end = (node + 1 < n_nodes) ? (excl[node + 1] + bsum[(node + 1) >> 10]) : E;

    float ax[8], ay[8];
#pragma unroll
    for (int j = 0; j < 8; ++j) { ax[j] = 0.f; ay[j] = 0.f; }

    int s = beg;
    for (; s + 8 <= end; s += 8) {
        u64 e[8];
#pragma unroll
        for (int j = 0; j < 8; ++j) e[j] = __builtin_nontemporal_load(edges + s + j);
#pragma unroll
        for (int j = 0; j < 8; ++j) gstep(e[j], Fb, lane, ax[j], ay[j]);
    }
    if (s + 4 <= end) {
        u64 e[4];
#pragma unroll
        for (int j = 0; j < 4; ++j) e[j] = __builtin_nontemporal_load(edges + s + j);
#pragma unroll
        for (int j = 0; j < 4; ++j) gstep(e[j], Fb, lane, ax[j], ay[j]);
        s += 4;
    }
    if (s + 2 <= end) {
        u64 e0 = __builtin_nontemporal_load(edges + s);
        u64 e1 = __builtin_nontemporal_load(edges + s + 1);
        gstep(e0, Fb, lane, ax[0], ay[0]);
        gstep(e1, Fb, lane, ax[1], ay[1]);
        s += 2;
    }
    if (s < end) {
        u64 e0 = __builtin_nontemporal_load(edges + s);
        gstep(e0, Fb, lane, ax[0], ay[0]);
    }
#pragma unroll
    for (int j = 4; j < 8; ++j) { ax[j - 4] += ax[j]; ay[j - 4] += ay[j]; }
    float axs = (ax[0] + ax[1]) + (ax[2] + ax[3]);
    float ays = (ay[0] + ay[1]) + (ay[2] + ay[3]);
    float inv = 1.f / fmaxf((float)(end - beg), 1.f);
    unsigned int lo = (unsigned int)(unsigned short)f2bf(axs * inv);
    unsigned int hi = (unsigned int)(unsigned short)f2bf(ays * inv);
    outb[(size_t)node * 64 + lane] = lo | (hi << 16);
}

// ---------------- MFMA linears ----------------
// mfma_f32_16x16x32_bf16: A row=l&15, k=8*(l>>4)+j ; B col=l&15; C/D col=lane&15,
// row=(lane>>4)*4+reg [learn_hip m89]. Block = 4 waves, 64 nodes.

__global__ __launch_bounds__(256)
void linear1_mfma(const __hip_bfloat16* __restrict__ Ab1,  // mean1b [N,128]
                  const __hip_bfloat16* __restrict__ Ab2,  // xb [N,128]
                  const __hip_bfloat16* __restrict__ Wb,
                  const float* __restrict__ bias,          // [128]
                  __hip_bfloat16* __restrict__ outb,       // hb [N,128]
                  int n_nodes) {
    int wid  = threadIdx.x >> 6;
    int lane = threadIdx.x & 63;
    int nodeBase = blockIdx.x * 64 + wid * 16;
    int m  = lane & 15;
    int kq = lane >> 4;
    int node = nodeBase + m;
    int nodeC = (node < n_nodes) ? node : (n_nodes - 1);

    short8 a1[4], a2[4];
    const short* A1p = (const short*)Ab1 + (size_t)nodeC * 128 + kq * 8;
    const short* A2p = (const short*)Ab2 + (size_t)nodeC * 128 + kq * 8;
#pragma unroll
    for (int kk = 0; kk < 4; ++kk) {
        a1[kk] = *(const short8*)(A1p + kk * 32);
        a2[kk] = *(const short8*)(A2p + kk * 32);
    }
    const short* Wrel  = (const short*)Wb;           // W1_rel
    const short* Wroot = (const short*)Wb + 16384;   // W1_root

#pragma unroll
    for (int c = 0; c < 8; ++c) {
        f32x4 acc = {0.f, 0.f, 0.f, 0.f};
        const short* b1p = Wrel  + (size_t)(c * 16 + m) * 128 + kq * 8;
        const short* b2p = Wroot + (size_t)(c * 16 + m) * 128 + kq * 8;
#pragma unroll
        for (int kk = 0; kk < 4; ++kk) {
            short8 bw1 = *(const short8*)(b1p + kk * 32);
            acc = __builtin_amdgcn_mfma_f32_16x16x32_bf16(a1[kk], bw1, acc, 0, 0, 0);
            short8 bw2 = *(const short8*)(b2p + kk * 32);
            acc = __builtin_amdgcn_mfma_f32_16x16x32_bf16(a2[kk], bw2, acc, 0, 0, 0);
        }
        int col = c * 16 + m;
        float b = bias[col];
#pragma unroll
        for (int i = 0; i < 4; ++i) {
            int gn = nodeBase + kq * 4 + i;
            if (gn < n_nodes) {
                float v = acc[i] + b;
                v = (v > 0.f) ? v : expm1f(v);
                outb[(size_t)gn * 128 + col] = __float2bfloat16(v);
            }
        }
    }
}

__global__ __launch_bounds__(256)
void linear2_mfma(const __hip_bfloat16* __restrict__ Ab1,  // mean2b [N,128]
                  const __hip_bfloat16* __restrict__ Ab2,  // hb [N,128]
                  const __hip_bfloat16* __restrict__ Wb,
                  const float* __restrict__ bmu, const float* __restrict__ blv,
                  float* __restrict__ out,                 // mu@0, lv@N*64
                  int n_nodes) {
    int wid  = threadIdx.x >> 6;
    int lane = threadIdx.x & 63;
    int nodeBase = blockIdx.x * 64 + wid * 16;
    int m  = lane & 15;
    int kq = lane >> 4;
    int node = nodeBase + m;
    int nodeC = (node < n_nodes) ? node : (n_nodes - 1);

    short8 a1[4], a2[4];
    const short* A1p = (const short*)Ab1 + (size_t)nodeC * 128 + kq * 8;
    const short* A2p = (const short*)Ab2 + (size_t)nodeC * 128 + kq * 8;
#pragma unroll
    for (int kk = 0; kk < 4; ++kk) {
        a1[kk] = *(const short8*)(A1p + kk * 32);
        a2[kk] = *(const short8*)(A2p + kk * 32);
    }
    const short* WmuR = (const short*)Wb + 32768;
    const short* WmuT = (const short*)Wb + 40960;
    const short* WlvR = (const short*)Wb + 49152;
    const short* WlvT = (const short*)Wb + 57344;

#pragma unroll
    for (int c = 0; c < 4; ++c) {
        f32x4 accMu = {0.f, 0.f, 0.f, 0.f};
        f32x4 accLv = {0.f, 0.f, 0.f, 0.f};
        size_t wrow = (size_t)(c * 16 + m) * 128 + kq * 8;
#pragma unroll
        for (int kk = 0; kk < 4; ++kk) {
            short8 bm1 = *(const short8*)(WmuR + wrow + kk * 32);
            accMu = __builtin_amdgcn_mfma_f32_16x16x32_bf16(a1[kk], bm1, accMu, 0, 0, 0);
            short8 bm2 = *(const short8*)(WmuT + wrow + kk * 32);
            accMu = __builtin_amdgcn_mfma_f32_16x16x32_bf16(a2[kk], bm2, accMu, 0, 0, 0);
            short8 bl1 = *(const short8*)(WlvR + wrow + kk * 32);
            accLv = __builtin_amdgcn_mfma_f32_16x16x32_bf16(a1[kk], bl1, accLv, 0, 0, 0);
            short8 bl2 = *(const short8*)(WlvT + wrow + kk * 32);
            accLv = __builtin_amdgcn_mfma_f32_16x16x32_bf16(a2[kk], bl2, accLv, 0, 0, 0);
        }
        int col = c * 16 + m;
        float bm = bmu[col], bl = blv[col];
#pragma unroll
        for (int i = 0; i < 4; ++i) {
            int gn = nodeBase + kq * 4 + i;
            if (gn < n_nodes) {
                out[(size_t)gn * 64 + col] = accMu[i] + bm;
                out[(size_t)NNODES * 64 + (size_t)gn * 64 + col] = accLv[i] + bl;
            }
        }
    }
}

extern "C" void kernel_launch(void* const* d_in, const int* in_sizes, int n_in,
                              void* d_out, int out_size, void* d_ws, size_t ws_size,
                              hipStream_t stream) {
    const float* x        = (const float*)d_in[0];
    const int*   eidx     = (const int*)d_in[1];
    const float* eattr    = (const float*)d_in[2];
    const float* W1_rel   = (const float*)d_in[3];
    const float* b1_rel   = (const float*)d_in[4];
    const float* W1_root  = (const float*)d_in[5];
    const float* Wmu_rel  = (const float*)d_in[6];
    const float* bmu_rel  = (const float*)d_in[7];
    const float* Wmu_root = (const float*)d_in[8];
    const float* Wlv_rel  = (const float*)d_in[9];
    const float* blv_rel  = (const float*)d_in[10];
    const float* Wlv_root = (const float*)d_in[11];
    float* out = (float*)d_out;

    const int N = NNODES, E = NEDGES;
    const int nb = (N + 1023) / 1024;   // 49
    const int* src = eidx;
    const int* dst = eidx + E;

    char* ws = (char*)d_ws;
    size_t off = 0;
    int* excl = (int*)(ws + off); off += (size_t)N * 4;
    int* bsum = (int*)(ws + off); off += 256;
    off = (off + 63) & ~(size_t)63;
    unsigned int* partial = (unsigned int*)(ws + off); off += (size_t)NC * (N / 4) * 4;  // 3.2MB
    unsigned char* cbase  = (unsigned char*)(ws + off); off += (size_t)N * NC;           // 3.2MB
    u64* edges = (u64*)(ws + off); off += (size_t)E * 8;
    __hip_bfloat16* xb    = (__hip_bfloat16*)(ws + off); off += (size_t)N * 128 * 2;
    __hip_bfloat16* meanb = (__hip_bfloat16*)(ws + off); off += (size_t)N * 128 * 2;
    __hip_bfloat16* hb    = (__hip_bfloat16*)(ws + off); off += (size_t)N * 128 * 2;
    __hip_bfloat16* Wb    = (__hip_bfloat16*)(ws + off); off += 65536 * 2;

    // prep: cvt_x | cvt_weights
    prep_kernel<<<3381, 256, 0, stream>>>(x, xb, W1_rel, W1_root, Wmu_rel, Wmu_root,
                                          Wlv_rel, Wlv_root, Wb);
    // CSR build, atomic-free
    hist_kernel<<<NC, 256, 0, stream>>>(dst, partial);
    scan1_kernel<<<nb, 1024, 0, stream>>>(partial, cbase, excl, bsum);
    scan2_kernel<<<1, 64, 0, stream>>>(bsum, nb);
    fill_kernel<<<NC * 8, 256, 0, stream>>>(src, dst, eattr, excl, bsum, cbase, edges);

    // pass 1: mean of xb
    gather_mean_kernel<<<(N * 64 + 255) / 256, 256, 0, stream>>>(
        (const unsigned int*)xb, excl, bsum, edges, (unsigned int*)meanb, N, E);
    // h = elu(linear)
    linear1_mfma<<<(N + 63) / 64, 256, 0, stream>>>(meanb, xb, Wb, b1_rel, hb, N);
    // pass 2: mean of hb (reuse meanb)
    gather_mean_kernel<<<(N * 64 + 255) / 256, 256, 0, stream>>>(
        (const unsigned int*)hb, excl, bsum, edges, (unsigned int*)meanb, N, E);
    // mu + logvar fused
    linear2_mfma<<<(N + 63) / 64, 256, 0, stream>>>(meanb, hb, Wb, bmu_rel, blv_rel, out, N);
}

// Round 8
// 213.413 us; speedup vs baseline: 38.7558x; 1.1039x over previous
//
#include <hip/hip_runtime.h>
#include <hip/hip_bf16.h>
#include <math.h>

#define NNODES 50000
#define NEDGES 800000
#define NRANGE 6250          // NNODES / 8 (exact)
#define NC     64            // edge chunks
#define CHUNK_E (NEDGES / NC)   // 12500 exact
#define NSLICE 4
#define SLICE_E (CHUNK_E / NSLICE)  // 3125

using short8 = __attribute__((ext_vector_type(8))) short;
using f32x4  = __attribute__((ext_vector_type(4))) float;
typedef unsigned long long u64;

__device__ __forceinline__ short f2bf(float f) {
    __hip_bfloat16 h = __float2bfloat16(f);
    return *reinterpret_cast<short*>(&h);
}

// ---------------- prep: cvt_x | cvt_weights (no atomics, no LDS) ----------------
// Wb layout (elems): W1_rel@0, W1_root@16384, Wmu_rel@32768, Wmu_root@40960,
//                    Wlv_rel@49152, Wlv_root@57344  (total 65536)

__global__ __launch_bounds__(256)
void prep_kernel(const float* __restrict__ x, __hip_bfloat16* __restrict__ xb,
                 const float* __restrict__ w0, const float* __restrict__ w1,
                 const float* __restrict__ w2, const float* __restrict__ w3,
                 const float* __restrict__ w4, const float* __restrict__ w5,
                 __hip_bfloat16* __restrict__ Wb) {
    int b = blockIdx.x;
    int tid = threadIdx.x;
    if (b < 3125) {                       // cvt x: 800000 short8 items
        int i = b * 256 + tid;
        const float4* p = (const float4*)x + (size_t)i * 2;
        float4 a = p[0], c = p[1];
        short8 o;
        o[0] = f2bf(a.x); o[1] = f2bf(a.y); o[2] = f2bf(a.z); o[3] = f2bf(a.w);
        o[4] = f2bf(c.x); o[5] = f2bf(c.y); o[6] = f2bf(c.z); o[7] = f2bf(c.w);
        *reinterpret_cast<short8*>((short*)xb + (size_t)i * 8) = o;
    } else {                              // cvt weights: 65536 elems
        int i = (b - 3125) * 256 + tid;
        const float* src; int off;
        if      (i < 16384) { src = w0; off = 0; }
        else if (i < 32768) { src = w1; off = 16384; }
        else if (i < 40960) { src = w2; off = 32768; }
        else if (i < 49152) { src = w3; off = 40960; }
        else if (i < 57344) { src = w4; off = 49152; }
        else                { src = w5; off = 57344; }
        Wb[i] = __float2bfloat16(src[i - off]);
    }
}

// ---------------- hist: per-chunk LDS histogram + PER-EDGE RANK, no global atomics -
// The LDS atomicAdd's returned old count IS the edge's rank within (chunk,node);
// persisting it (rank8) turns fill into a pure map (r7: fill was parallelism-
// starved at 512 blocks because LDS cursors pinned one block per chunk-range).

__global__ __launch_bounds__(256)
void hist_kernel(const int* __restrict__ dst, unsigned int* __restrict__ partial,
                 unsigned char* __restrict__ rank8) {
    __shared__ unsigned int hist[NNODES / 4];   // 12500 u32 = 50KB
    int c = blockIdx.x;
    int tid = threadIdx.x;
    for (int i = tid; i < NNODES / 4; i += 256) hist[i] = 0;
    __syncthreads();
    int base = c * CHUNK_E;
    for (int e = base + tid; e < base + CHUNK_E; e += 256) {
        int d = dst[e];
        int sh = 8 * (d & 3);
        unsigned int old = atomicAdd(&hist[d >> 2], 1u << sh);
        rank8[e] = (unsigned char)((old >> sh) & 0xffu);
    }
    __syncthreads();
    unsigned int* outp = partial + (size_t)c * (NNODES / 4);
    for (int i = tid; i < NNODES / 4; i += 256) outp[i] = hist[i];
}

// ---------------- scan1: degrees from partials + per-chunk bases + block scan ----

__global__ __launch_bounds__(1024)
void scan1_kernel(const unsigned int* __restrict__ partial,
                  unsigned char* __restrict__ cbase,   // [N][NC] u8, 64B/node
                  int* __restrict__ excl, int* __restrict__ bsum) {
    __shared__ int sdata[1024];
    int tid = threadIdx.x;
    int n = blockIdx.x * 1024 + tid;
    int deg = 0;
    if (n < NNODES) {
        int sh = 8 * (n & 3);
        int idx = n >> 2;
        unsigned int packed = 0;
        unsigned int* cbout = (unsigned int*)(cbase + (size_t)n * NC);
#pragma unroll 4
        for (int c = 0; c < NC; ++c) {
            unsigned int w = partial[(size_t)c * (NNODES / 4) + idx];
            unsigned int cc = (w >> sh) & 0xffu;
            packed |= ((unsigned int)(deg & 0xff)) << (8 * (c & 3));   // excl base
            deg += (int)cc;
            if ((c & 3) == 3) { cbout[c >> 2] = packed; packed = 0; }
        }
    }
    sdata[tid] = deg;
    __syncthreads();
    for (int off = 1; off < 1024; off <<= 1) {
        int t = (tid >= off) ? sdata[tid - off] : 0;
        __syncthreads();
        sdata[tid] += t;
        __syncthreads();
    }
    if (n < NNODES) excl[n] = sdata[tid] - deg;
    if (tid == 1023) bsum[blockIdx.x] = sdata[1023];
}

// single-wave shfl scan over nb (<=64) block sums
__global__ __launch_bounds__(64)
void scan2_kernel(int* __restrict__ bsum, int nb) {
    int lane = threadIdx.x;
    int v = (lane < nb) ? bsum[lane] : 0;
    int incl = v;
    for (int off = 1; off < 64; off <<= 1) {
        int t = __shfl_up(incl, off);
        if (lane >= off) incl += t;
    }
    if (lane < nb) bsum[lane] = incl - v;   // exclusive
    if (lane == 63) bsum[nb] = incl;        // total
}

// ---------------- fill: pure-map CSR scatter, XCD-partitioned, slice-parallel ----
// block b: range r=b&7 (XCD-local writes under round-robin), t=b>>3: chunk c=t&63,
// slice s=t>>6. slot = excl[d]+bsum[d>>10]+cbase[d][c]+rank8[e]. No LDS, no
// atomics -> 2048 blocks (8/CU) vs r7's 512 (latency-starved at 2/CU).

__global__ __launch_bounds__(256)
void fill_kernel(const int* __restrict__ src, const int* __restrict__ dst,
                 const float* __restrict__ ew,
                 const int* __restrict__ excl, const int* __restrict__ bsum,
                 const unsigned char* __restrict__ cbase,
                 const unsigned char* __restrict__ rank8,
                 u64* __restrict__ edges) {
    int b = blockIdx.x;
    int r = b & 7;
    int t = b >> 3;
    int c = t & (NC - 1);
    int s = t >> 6;
    int lo = r * NRANGE;
    int base = c * CHUNK_E + s * SLICE_E;
    int end = base + SLICE_E;
    for (int e = base + threadIdx.x; e < end; e += 256) {
        int d = dst[e];
        unsigned int dl = (unsigned int)(d - lo);
        if (dl < NRANGE) {
            int slot = excl[d] + bsum[d >> 10] + (int)cbase[(size_t)d * NC + c] + (int)rank8[e];
            u64 pack = ((u64)(unsigned int)__float_as_int(ew[e]) << 32) | (unsigned int)src[e];
            edges[slot] = pack;
        }
    }
}

// ---------------- scatter-mean as node-centric gather (bf16 features) ----------------
// one wave per node; lane owns 2 bf16 features (one uint). fp32 accumulate.
// 8 independent accumulator chains; beg/end readfirstlane'd so the per-wave-
// uniform edge-stream loads can go scalar.

__device__ __forceinline__ void gstep(u64 e, const unsigned int* __restrict__ Fb,
                                      int lane, float& ax, float& ay) {
    unsigned int v = Fb[(size_t)(unsigned int)e * 64 + lane];
    float w = __uint_as_float((unsigned int)(e >> 32));
    ax += __uint_as_float(v << 16) * w;
    ay += __uint_as_float(v & 0xffff0000u) * w;
}

__global__ __launch_bounds__(256)
void gather_mean_kernel(const unsigned int* __restrict__ Fb,   // [N,64] uints = [N,128] bf16
                        const int* __restrict__ excl, const int* __restrict__ bsum,
                        const u64* __restrict__ edges,
                        unsigned int* __restrict__ outb,       // [N,64] uints
                        int n_nodes, int E) {
    int node = (blockIdx.x * blockDim.x + threadIdx.x) >> 6;
    int lane = threadIdx.x & 63;
    if (node >= n_nodes) return;
    int beg = excl[node] + bsum[node >> 10];
    int end = (node + 1 < n_nodes) ? (excl[node + 1] + bsum[(node + 1) >> 10]) : E;
    beg = __builtin_amdgcn_readfirstlane(beg);
    end = __builtin_amdgcn_readfirstlane(end);

    float ax[8], ay[8];
#pragma unroll
    for (int j = 0; j < 8; ++j) { ax[j] = 0.f; ay[j] = 0.f; }

    int s = beg;
    for (; s + 8 <= end; s += 8) {
        u64 e[8];
#pragma unroll
        for (int j = 0; j < 8; ++j) e[j] = __builtin_nontemporal_load(edges + s + j);
#pragma unroll
        for (int j = 0; j < 8; ++j) gstep(e[j], Fb, lane, ax[j], ay[j]);
    }
    if (s + 4 <= end) {
        u64 e[4];
#pragma unroll
        for (int j = 0; j < 4; ++j) e[j] = __builtin_nontemporal_load(edges + s + j);
#pragma unroll
        for (int j = 0; j < 4; ++j) gstep(e[j], Fb, lane, ax[j], ay[j]);
        s += 4;
    }
    if (s + 2 <= end) {
        u64 e0 = __builtin_nontemporal_load(edges + s);
        u64 e1 = __builtin_nontemporal_load(edges + s + 1);
        gstep(e0, Fb, lane, ax[0], ay[0]);
        gstep(e1, Fb, lane, ax[1], ay[1]);
        s += 2;
    }
    if (s < end) {
        u64 e0 = __builtin_nontemporal_load(edges + s);
        gstep(e0, Fb, lane, ax[0], ay[0]);
    }
#pragma unroll
    for (int j = 4; j < 8; ++j) { ax[j - 4] += ax[j]; ay[j - 4] += ay[j]; }
    float axs = (ax[0] + ax[1]) + (ax[2] + ax[3]);
    float ays = (ay[0] + ay[1]) + (ay[2] + ay[3]);
    float inv = 1.f / fmaxf((float)(end - beg), 1.f);
    unsigned int lo = (unsigned int)(unsigned short)f2bf(axs * inv);
    unsigned int hi = (unsigned int)(unsigned short)f2bf(ays * inv);
    outb[(size_t)node * 64 + lane] = lo | (hi << 16);
}

// ---------------- MFMA linears ----------------
// mfma_f32_16x16x32_bf16: A row=l&15, k=8*(l>>4)+j ; B col=l&15; C/D col=lane&15,
// row=(lane>>4)*4+reg [learn_hip m89]. Block = 4 waves, 64 nodes.

__global__ __launch_bounds__(256)
void linear1_mfma(const __hip_bfloat16* __restrict__ Ab1,  // mean1b [N,128]
                  const __hip_bfloat16* __restrict__ Ab2,  // xb [N,128]
                  const __hip_bfloat16* __restrict__ Wb,
                  const float* __restrict__ bias,          // [128]
                  __hip_bfloat16* __restrict__ outb,       // hb [N,128]
                  int n_nodes) {
    int wid  = threadIdx.x >> 6;
    int lane = threadIdx.x & 63;
    int nodeBase = blockIdx.x * 64 + wid * 16;
    int m  = lane & 15;
    int kq = lane >> 4;
    int node = nodeBase + m;
    int nodeC = (node < n_nodes) ? node : (n_nodes - 1);

    short8 a1[4], a2[4];
    const short* A1p = (const short*)Ab1 + (size_t)nodeC * 128 + kq * 8;
    const short* A2p = (const short*)Ab2 + (size_t)nodeC * 128 + kq * 8;
#pragma unroll
    for (int kk = 0; kk < 4; ++kk) {
        a1[kk] = *(const short8*)(A1p + kk * 32);
        a2[kk] = *(const short8*)(A2p + kk * 32);
    }
    const short* Wrel  = (const short*)Wb;           // W1_rel
    const short* Wroot = (const short*)Wb + 16384;   // W1_root

#pragma unroll
    for (int c = 0; c < 8; ++c) {
        f32x4 acc = {0.f, 0.f, 0.f, 0.f};
        const short* b1p = Wrel  + (size_t)(c * 16 + m) * 128 + kq * 8;
        const short* b2p = Wroot + (size_t)(c * 16 + m) * 128 + kq * 8;
#pragma unroll
        for (int kk = 0; kk < 4; ++kk) {
            short8 bw1 = *(const short8*)(b1p + kk * 32);
            acc = __builtin_amdgcn_mfma_f32_16x16x32_bf16(a1[kk], bw1, acc, 0, 0, 0);
            short8 bw2 = *(const short8*)(b2p + kk * 32);
            acc = __builtin_amdgcn_mfma_f32_16x16x32_bf16(a2[kk], bw2, acc, 0, 0, 0);
        }
        int col = c * 16 + m;
        float b = bias[col];
#pragma unroll
        for (int i = 0; i < 4; ++i) {
            int gn = nodeBase + kq * 4 + i;
            if (gn < n_nodes) {
                float v = acc[i] + b;
                v = (v > 0.f) ? v : expm1f(v);
                outb[(size_t)gn * 128 + col] = __float2bfloat16(v);
            }
        }
    }
}

__global__ __launch_bounds__(256)
void linear2_mfma(const __hip_bfloat16* __restrict__ Ab1,  // mean2b [N,128]
                  const __hip_bfloat16* __restrict__ Ab2,  // hb [N,128]
                  const __hip_bfloat16* __restrict__ Wb,
                  const float* __restrict__ bmu, const float* __restrict__ blv,
                  float* __restrict__ out,                 // mu@0, lv@N*64
                  int n_nodes) {
    int wid  = threadIdx.x >> 6;
    int lane = threadIdx.x & 63;
    int nodeBase = blockIdx.x * 64 + wid * 16;
    int m  = lane & 15;
    int kq = lane >> 4;
    int node = nodeBase + m;
    int nodeC = (node < n_nodes) ? node : (n_nodes - 1);

    short8 a1[4], a2[4];
    const short* A1p = (const short*)Ab1 + (size_t)nodeC * 128 + kq * 8;
    const short* A2p = (const short*)Ab2 + (size_t)nodeC * 128 + kq * 8;
#pragma unroll
    for (int kk = 0; kk < 4; ++kk) {
        a1[kk] = *(const short8*)(A1p + kk * 32);
        a2[kk] = *(const short8*)(A2p + kk * 32);
    }
    const short* WmuR = (const short*)Wb + 32768;
    const short* WmuT = (const short*)Wb + 40960;
    const short* WlvR = (const short*)Wb + 49152;
    const short* WlvT = (const short*)Wb + 57344;

#pragma unroll
    for (int c = 0; c < 4; ++c) {
        f32x4 accMu = {0.f, 0.f, 0.f, 0.f};
        f32x4 accLv = {0.f, 0.f, 0.f, 0.f};
        size_t wrow = (size_t)(c * 16 + m) * 128 + kq * 8;
#pragma unroll
        for (int kk = 0; kk < 4; ++kk) {
            short8 bm1 = *(const short8*)(WmuR + wrow + kk * 32);
            accMu = __builtin_amdgcn_mfma_f32_16x16x32_bf16(a1[kk], bm1, accMu, 0, 0, 0);
            short8 bm2 = *(const short8*)(WmuT + wrow + kk * 32);
            accMu = __builtin_amdgcn_mfma_f32_16x16x32_bf16(a2[kk], bm2, accMu, 0, 0, 0);
            short8 bl1 = *(const short8*)(WlvR + wrow + kk * 32);
            accLv = __builtin_amdgcn_mfma_f32_16x16x32_bf16(a1[kk], bl1, accLv, 0, 0, 0);
            short8 bl2 = *(const short8*)(WlvT + wrow + kk * 32);
            accLv = __builtin_amdgcn_mfma_f32_16x16x32_bf16(a2[kk], bl2, accLv, 0, 0, 0);
        }
        int col = c * 16 + m;
        float bm = bmu[col], bl = blv[col];
#pragma unroll
        for (int i = 0; i < 4; ++i) {
            int gn = nodeBase + kq * 4 + i;
            if (gn < n_nodes) {
                out[(size_t)gn * 64 + col] = accMu[i] + bm;
                out[(size_t)NNODES * 64 + (size_t)gn * 64 + col] = accLv[i] + bl;
            }
        }
    }
}

extern "C" void kernel_launch(void* const* d_in, const int* in_sizes, int n_in,
                              void* d_out, int out_size, void* d_ws, size_t ws_size,
                              hipStream_t stream) {
    const float* x        = (const float*)d_in[0];
    const int*   eidx     = (const int*)d_in[1];
    const float* eattr    = (const float*)d_in[2];
    const float* W1_rel   = (const float*)d_in[3];
    const float* b1_rel   = (const float*)d_in[4];
    const float* W1_root  = (const float*)d_in[5];
    const float* Wmu_rel  = (const float*)d_in[6];
    const float* bmu_rel  = (const float*)d_in[7];
    const float* Wmu_root = (const float*)d_in[8];
    const float* Wlv_rel  = (const float*)d_in[9];
    const float* blv_rel  = (const float*)d_in[10];
    const float* Wlv_root = (const float*)d_in[11];
    float* out = (float*)d_out;

    const int N = NNODES, E = NEDGES;
    const int nb = (N + 1023) / 1024;   // 49
    const int* src = eidx;
    const int* dst = eidx + E;

    char* ws = (char*)d_ws;
    size_t off = 0;
    int* excl = (int*)(ws + off); off += (size_t)N * 4;
    int* bsum = (int*)(ws + off); off += 256;
    off = (off + 63) & ~(size_t)63;
    unsigned int* partial = (unsigned int*)(ws + off); off += (size_t)NC * (N / 4) * 4;  // 3.2MB
    unsigned char* cbase  = (unsigned char*)(ws + off); off += (size_t)N * NC;           // 3.2MB
    unsigned char* rank8  = (unsigned char*)(ws + off); off += (size_t)E;                // 0.8MB
    off = (off + 63) & ~(size_t)63;
    u64* edges = (u64*)(ws + off); off += (size_t)E * 8;
    __hip_bfloat16* xb    = (__hip_bfloat16*)(ws + off); off += (size_t)N * 128 * 2;
    __hip_bfloat16* meanb = (__hip_bfloat16*)(ws + off); off += (size_t)N * 128 * 2;
    __hip_bfloat16* hb    = (__hip_bfloat16*)(ws + off); off += (size_t)N * 128 * 2;
    __hip_bfloat16* Wb    = (__hip_bfloat16*)(ws + off); off += 65536 * 2;

    // prep: cvt_x | cvt_weights
    prep_kernel<<<3381, 256, 0, stream>>>(x, xb, W1_rel, W1_root, Wmu_rel, Wmu_root,
                                          Wlv_rel, Wlv_root, Wb);
    // CSR build, atomic-free
    hist_kernel<<<NC, 256, 0, stream>>>(dst, partial, rank8);
    scan1_kernel<<<nb, 1024, 0, stream>>>(partial, cbase, excl, bsum);
    scan2_kernel<<<1, 64, 0, stream>>>(bsum, nb);
    fill_kernel<<<NC * 8 * NSLICE, 256, 0, stream>>>(src, dst, eattr, excl, bsum,
                                                     cbase, rank8, edges);

    // pass 1: mean of xb
    gather_mean_kernel<<<(N * 64 + 255) / 256, 256, 0, stream>>>(
        (const unsigned int*)xb, excl, bsum, edges, (unsigned int*)meanb, N, E);
    // h = elu(linear)
    linear1_mfma<<<(N + 63) / 64, 256, 0, stream>>>(meanb, xb, Wb, b1_rel, hb, N);
    // pass 2: mean of hb (reuse meanb)
    gather_mean_kernel<<<(N * 64 + 255) / 256, 256, 0, stream>>>(
        (const unsigned int*)hb, excl, bsum, edges, (unsigned int*)meanb, N, E);
    // mu + logvar fused
    linear2_mfma<<<(N + 63) / 64, 256, 0, stream>>>(meanb, hb, Wb, bmu_rel, blv_rel, out, N);
}